// Round 9
// baseline (1126.707 us; speedup 1.0000x reference)
//
#include <hip/hip_runtime.h>

constexpr int NC = 100000;
constexpr int NQ = 20000;
constexpr int FC = 300;
constexpr int FQ = 768;
constexpr int NEDGE = 400000;
constexpr int NTOT = NC + NC + NQ;   // concatenated dst segments: et0 | et1 | et2
constexpr int NTOT2 = NC + NQ;       // all nodes (context then question)
constexpr int NB0 = (NC + 127) / 128;  // 782
constexpr int NB1 = (NQ + 127) / 128;  // 157
constexpr int NBALL = NB0 + NB1;       // 939
constexpr int NBC64 = (NC + 63) / 64;  // 1563
constexpr int NBQ64 = (NQ + 63) / 64;  // 313
constexpr int NBALL64 = NBC64 + NBQ64; // 1876
constexpr float SCALE = 0.17677669529663687f;  // 1/sqrt(32)
constexpr float LOG2E = 1.4426950408889634f;

typedef __attribute__((ext_vector_type(8))) short bf16x8;
typedef __attribute__((ext_vector_type(4))) float f32x4;
typedef unsigned short u16;

__device__ __forceinline__ float gelu_f(float x) {
  return 0.5f * x * (1.0f + erff(x * 0.7071067811865476f));
}
__device__ __forceinline__ u16 bf16_rne(float x) {
  unsigned u = __float_as_uint(x);
  unsigned r = u + 0x7fffu + ((u >> 16) & 1u);
  return (u16)(r >> 16);
}
__device__ __forceinline__ float bf16_to_f(u16 h) {
  return __uint_as_float(((unsigned)h) << 16);
}
__device__ __forceinline__ void split2(float x, u16& hi, u16& lo) {
  hi = bf16_rne(x);
  lo = bf16_rne(x - bf16_to_f(hi));
}
__device__ __forceinline__ void splitT(float x, u16& hi, u16& lo) {
  hi = (u16)(__float_as_uint(x) >> 16);
  lo = bf16_rne(x - bf16_to_f(hi));
}

// ---------------- fused CSR build over 3 edge types ----------------
__global__ void k_count3(const int* __restrict__ d0, const int* __restrict__ d1,
                         const int* __restrict__ d2, int* __restrict__ counts) {
  int i = blockIdx.x * 256 + threadIdx.x;
  if (i >= 3 * NEDGE) return;
  int et = i / NEDGE, e = i - et * NEDGE;
  int d = (et == 0) ? d0[e] : (et == 1) ? d1[e] : d2[e];
  int base = (et == 0) ? 0 : (et == 1) ? NC : 2 * NC;
  atomicAdd(&counts[base + d], 1);
}

__global__ void k_scan_block(const int* __restrict__ in, int* __restrict__ out,
                             int* __restrict__ bsum, int n) {
  __shared__ int s[256];
  int tid = threadIdx.x;
  int i = blockIdx.x * 256 + tid;
  int v = (i < n) ? in[i] : 0;
  s[tid] = v;
  __syncthreads();
  for (int off = 1; off < 256; off <<= 1) {
    int t = (tid >= off) ? s[tid - off] : 0;
    __syncthreads();
    s[tid] += t;
    __syncthreads();
  }
  if (i < n) out[i] = s[tid] - v;
  if (tid == 255) bsum[blockIdx.x] = s[255];
}

__global__ void k_scan_sums(int* __restrict__ bsum, int nb) {
  __shared__ int s[1024];
  int tid = threadIdx.x;
  int v = (tid < nb) ? bsum[tid] : 0;
  s[tid] = v;
  __syncthreads();
  for (int off = 1; off < 1024; off <<= 1) {
    int t = (tid >= off) ? s[tid - off] : 0;
    __syncthreads();
    s[tid] += t;
    __syncthreads();
  }
  if (tid < nb) bsum[tid] = s[tid] - v;
}

__global__ void k_scan_add(int* __restrict__ ptr, const int* __restrict__ bsum,
                           int* __restrict__ cursor, int n, int total) {
  int i = blockIdx.x * 256 + threadIdx.x;
  if (i < n) {
    int v = ptr[i] + bsum[blockIdx.x];
    ptr[i] = v;
    cursor[i] = v;
  }
  if (i == 0) ptr[n] = total;
}

__global__ void k_scatter3(const int* __restrict__ s0, const int* __restrict__ s1,
                           const int* __restrict__ s2, const int* __restrict__ d0,
                           const int* __restrict__ d1, const int* __restrict__ d2,
                           int* __restrict__ cursor, int* __restrict__ srcs_out) {
  int i = blockIdx.x * 256 + threadIdx.x;
  if (i >= 3 * NEDGE) return;
  int et = i / NEDGE, e = i - et * NEDGE;
  int d = (et == 0) ? d0[e] : (et == 1) ? d1[e] : d2[e];
  int sv = (et == 0) ? s0[e] : (et == 1) ? s1[e] : s2[e];
  int base = (et == 0) ? 0 : (et == 1) ? NC : 2 * NC;
  int p = atomicAdd(&cursor[base + d], 1);
  srcs_out[p] = sv;
}

// ---------------- B prep for BOTH layers: 20 slabs, Kp=128 ----------------
__global__ void prep_all(const float* __restrict__ kW, const float* __restrict__ kB,
                         const float* __restrict__ qW, const float* __restrict__ qB,
                         const float* __restrict__ vW, const float* __restrict__ vB,
                         const float* __restrict__ aW, const float* __restrict__ aB,
                         const float* __restrict__ arel, const float* __restrict__ mrel,
                         const float* __restrict__ prel,
                         u16* __restrict__ Bth, u16* __restrict__ Btl,
                         float* __restrict__ biasOut) {
  int i = blockIdx.x;     // input dim 0..127
  int col = threadIdx.x;  // output col 0..127
  int y = blockIdx.y;     // 0..19
  int l = y / 10, yy = y % 10;
  size_t lw = (size_t)l * 2 * 16384, lb = (size_t)l * 2 * 128;
  size_t le = (size_t)l * 3 * 4096, lp = (size_t)l * 3 * 4;
  const float *W = nullptr, *bb = nullptr, *rel = nullptr, *pr = nullptr;
  float mscale = 1.0f;
  bool fold = false;
  switch (yy) {
    case 0: W = qW + lw; bb = qB + lb; break;
    case 1: fold = true; W = kW + lw; bb = kB + lb; rel = arel + le + 4096; pr = prel + lp + 4; mscale = SCALE; break;
    case 2: fold = true; W = vW + lw; bb = vB + lb; rel = mrel + le + 4096; break;
    case 3: fold = true; W = kW + lw; bb = kB + lb; rel = arel + le + 8192; pr = prel + lp + 8; mscale = SCALE; break;
    case 4: fold = true; W = vW + lw; bb = vB + lb; rel = mrel + le + 8192; break;
    case 5: W = qW + lw + 16384; bb = qB + lb + 128; break;
    case 6: fold = true; W = kW + lw + 16384; bb = kB + lb + 128; rel = arel + le; pr = prel + lp; mscale = SCALE; break;
    case 7: fold = true; W = vW + lw + 16384; bb = vB + lb + 128; rel = mrel + le; break;
    case 8: W = aW + lw; bb = aB + lb; break;
    default: W = aW + lw + 16384; bb = aB + lb + 128; break;
  }
  int colOff = y * 128;
  if (!fold) {
    float v = W[i * 128 + col];
    u16 hi, lo;
    split2(v, hi, lo);
    Bth[(size_t)(colOff + col) * 128 + i] = hi;
    Btl[(size_t)(colOff + col) * 128 + i] = lo;
    if (i == 0) biasOut[colOff + col] = bb[col];
    return;
  }
  int h = col >> 5, f = col & 31;
  float m = (pr ? pr[h] : 1.0f) * mscale;
  float s = 0.0f;
  #pragma unroll
  for (int d = 0; d < 32; ++d)
    s += W[i * 128 + h * 32 + d] * rel[(h * 32 + d) * 32 + f];
  s *= m;
  u16 hi, lo;
  split2(s, hi, lo);
  Bth[(size_t)(colOff + col) * 128 + i] = hi;
  Btl[(size_t)(colOff + col) * 128 + i] = lo;
  if (i == 0) {
    float sb = 0.0f;
    #pragma unroll
    for (int d = 0; d < 32; ++d)
      sb += bb[h * 32 + d] * rel[(h * 32 + d) * 32 + f];
    biasOut[colOff + col] = sb * m;
  }
}

// ---------------- input weight split: y=0 context (K=300,Kp=320), y=1 question (768,768) ----
__global__ void split_in(const float* __restrict__ Wc, const float* __restrict__ bc,
                         const float* __restrict__ Wq, const float* __restrict__ bq,
                         u16* __restrict__ Bth, u16* __restrict__ Btl,
                         float* __restrict__ biasOut) {
  int n = blockIdx.x, y = blockIdx.y;
  const float* W = y ? Wq : Wc;
  const float* b = y ? bq : bc;
  int K = y ? FQ : FC, Kp = y ? 768 : 320;
  size_t boff = y ? (size_t)128 * 320 : 0;
  for (int k = threadIdx.x; k < Kp; k += 256) {
    float v = (k < K) ? W[(size_t)k * 128 + n] : 0.0f;
    u16 hi, lo;
    split2(v, hi, lo);
    Bth[boff + (size_t)n * Kp + k] = hi;
    Btl[boff + (size_t)n * Kp + k] = lo;
  }
  if (threadIdx.x == 0) biasOut[(y ? 128 : 0) + n] = b[n];
}

// ---------------- pipelined f32-A GEMM, BM=64, 3-term split, 2-deep prefetch ----------------
// MODE 1: input projections (relu)  MODE 2: a-projection (gelu on A; skip-gate)
template <int MODE>
__global__ __launch_bounds__(256) void pipe_gemm(
    const float* __restrict__ Ac, const float* __restrict__ Aq,
    const u16* __restrict__ Bth, const u16* __restrict__ Btl,
    const float* __restrict__ biasBuf,
    u16* __restrict__ xh_all, u16* __restrict__ xl_all,
    const float* __restrict__ skip, int l) {
  __shared__ u16 smem[15360];  // 30720 B: Ah@0 Al@2560 Bh@5120 Bl@10240 ; epi-stage reuses @0
  constexpr int AH = 0, AL = 2560, BH = 5120, BL = 10240;
  const int tid = threadIdx.x, lane = tid & 63, wv = tid >> 6;
  const int l15 = lane & 15, g4 = lane >> 4, koff = g4 * 8;
  const int srA = tid >> 2, scA = (tid & 3) * 8;   // A: 8 f32/thread
  const int srB = tid >> 1, scB = (tid & 1) * 16;  // B: 16 u16/thread/array

  const int bid = blockIdx.x;
  const int nt = (bid < NBC64) ? 0 : 1;
  const int m0 = nt ? (bid - NBC64) * 64 : bid * 64;
  const int M = nt ? NQ : NC;
  const int rowbase = nt ? NC : 0;
  const float* A32;
  int K, Kp, biasOff;
  size_t boff, arow;
  if (MODE == 1) {
    if (nt == 0) { A32 = Ac; K = FC; Kp = 320; boff = 0; biasOff = 0; }
    else { A32 = Aq; K = FQ; Kp = 768; boff = (size_t)128 * 320; biasOff = 128; }
    arow = (size_t)(m0 + srA) * K;
  } else {
    A32 = Ac;
    K = 128; Kp = 128;
    boff = (size_t)(8 + nt) * 16384;
    biasOff = (8 + nt) * 128;
    arow = (size_t)(rowbase + m0 + srA) * 128;
  }
  const bool rowokA = (m0 + srA) < M;
  const int nk = (K + 31) / 32;

  f32x4 acc[8];
  #pragma unroll
  for (int ni = 0; ni < 8; ++ni) acc[ni] = (f32x4){0.f, 0.f, 0.f, 0.f};

  auto loadA = [&](float va[8], int k0) {
    if (rowokA && (k0 + 32 <= K)) {
      const float* ap = A32 + arow + k0 + scA;
      float4 f0 = *(const float4*)ap;
      float4 f1 = *(const float4*)(ap + 4);
      va[0] = f0.x; va[1] = f0.y; va[2] = f0.z; va[3] = f0.w;
      va[4] = f1.x; va[5] = f1.y; va[6] = f1.z; va[7] = f1.w;
    } else {
      #pragma unroll
      for (int j = 0; j < 8; ++j) {
        int kc = k0 + scA + j;
        va[j] = (rowokA && kc < K) ? A32[arow + kc] : 0.0f;
      }
    }
  };
  auto loadB = [&](uint4 bt[4], int k0) {
    const u16* bp = Bth + boff + (size_t)srB * Kp + k0 + scB;
    bt[0] = *(const uint4*)bp;
    bt[1] = *(const uint4*)(bp + 8);
    const u16* lp = Btl + boff + (size_t)srB * Kp + k0 + scB;
    bt[2] = *(const uint4*)lp;
    bt[3] = *(const uint4*)(lp + 8);
  };

  float vaT[2][8];
  uint4 bT[2][4];
  loadA(vaT[0], 0);
  loadB(bT[0], 0);
  loadA(vaT[1], 32);
  loadB(bT[1], 32);

  for (int ks = 0; ks < nk; ++ks) {
    int cur = ks & 1;
    {
      alignas(16) u16 hv[8], lv[8];
      #pragma unroll
      for (int j = 0; j < 8; ++j) {
        float x = (MODE == 2) ? gelu_f(vaT[cur][j]) : vaT[cur][j];
        splitT(x, hv[j], lv[j]);
      }
      *(uint4*)&smem[AH + srA * 40 + scA] = *(const uint4*)hv;
      *(uint4*)&smem[AL + srA * 40 + scA] = *(const uint4*)lv;
      *(uint4*)&smem[BH + srB * 40 + scB] = bT[cur][0];
      *(uint4*)&smem[BH + srB * 40 + scB + 8] = bT[cur][1];
      *(uint4*)&smem[BL + srB * 40 + scB] = bT[cur][2];
      *(uint4*)&smem[BL + srB * 40 + scB + 8] = bT[cur][3];
    }
    __syncthreads();
    if (ks + 2 < nk) {
      loadA(vaT[cur], (ks + 2) * 32);
      loadB(bT[cur], (ks + 2) * 32);
    }
    {
      int row = wv * 16 + l15;
      bf16x8 a_h = *(const bf16x8*)&smem[AH + row * 40 + koff];
      bf16x8 a_l = *(const bf16x8*)&smem[AL + row * 40 + koff];
      #pragma unroll
      for (int ni = 0; ni < 8; ++ni) {
        int col = ni * 16 + l15;
        bf16x8 b_h = *(const bf16x8*)&smem[BH + col * 40 + koff];
        bf16x8 b_l = *(const bf16x8*)&smem[BL + col * 40 + koff];
        acc[ni] = __builtin_amdgcn_mfma_f32_16x16x32_bf16(a_h, b_h, acc[ni], 0, 0, 0);
        acc[ni] = __builtin_amdgcn_mfma_f32_16x16x32_bf16(a_l, b_h, acc[ni], 0, 0, 0);
        acc[ni] = __builtin_amdgcn_mfma_f32_16x16x32_bf16(a_h, b_l, acc[ni], 0, 0, 0);
      }
    }
    __syncthreads();
  }

  float g = 1.0f;
  if (MODE == 2) g = 1.0f / (1.0f + __expf(-skip[l * 2 + nt]));

  // finalize values in registers
  float ov[8][4];
  const int rl0 = wv * 16 + g4 * 4;
  #pragma unroll
  for (int ni = 0; ni < 8; ++ni) {
    int colL = ni * 16 + l15;
    float bi = biasBuf[biasOff + colL];
    #pragma unroll
    for (int rr = 0; rr < 4; ++rr) {
      int row = m0 + rl0 + rr;
      float o = acc[ni][rr] + bi;
      if (MODE == 1) {
        o = fmaxf(o, 0.0f);
      } else if (row < M) {
        size_t idx = (size_t)(rowbase + row) * 128 + colL;
        float xo = bf16_to_f(xh_all[idx]) + bf16_to_f(xl_all[idx]);
        o = g * o + (1.0f - g) * xo;
      }
      ov[ni][rr] = o;
    }
  }

  // staged coalesced epilogue: hi pass then lo pass
  const int wrow = tid >> 2, wseg = tid & 3;
  #pragma unroll
  for (int ph = 0; ph < 2; ++ph) {
    if (ph) __syncthreads();
    #pragma unroll
    for (int ni = 0; ni < 8; ++ni) {
      #pragma unroll
      for (int rr = 0; rr < 4; ++rr) {
        u16 hh, ll;
        split2(ov[ni][rr], hh, ll);
        smem[(rl0 + rr) * 136 + ni * 16 + l15] = ph ? ll : hh;
      }
    }
    __syncthreads();
    int grow = m0 + wrow;
    if (grow < M) {
      u16* dstp = ph ? xl_all : xh_all;
      uint4* dst = (uint4*)&dstp[(size_t)(rowbase + grow) * 128 + wseg * 32];
      const uint4* src = (const uint4*)&smem[wrow * 136 + wseg * 32];
      #pragma unroll
      for (int j = 0; j < 4; ++j) dst[j] = src[j];
    }
  }
}

// ---------------- q/kv projection GEMM: 1-term bf16, 2-deep prefetch, staged epilogue -------
__global__ __launch_bounds__(256) void proj_all(
    const u16* __restrict__ xh_all,
    const u16* __restrict__ Bth, const float* __restrict__ biasBuf,
    u16* __restrict__ q_all, u16* __restrict__ kvA,
    u16* __restrict__ kvB1, u16* __restrict__ kvB2) {
  int bid = blockIdx.x, y = blockIdx.y;
  int nt = (bid < NB0) ? 0 : 1;
  if (nt == 1 && y >= 3) return;
  __shared__ u16 smem[10240];  // Ah@0 [128][40], Bh@5120 [128][40]; epi reuses @0 [64][136]
  constexpr int AH = 0, BH = 5120;
  int m0 = nt ? (bid - NB0) * 128 : bid * 128;
  int M = nt ? NQ : NC;
  int abase = nt ? NC : 0;
  int bslab = nt ? 5 + y : y;
  u16* cp; int ld, cb, crowbase;
  if (nt == 0) {
    switch (y) {
      case 0: cp = q_all; ld = 128; cb = 0; crowbase = 0; break;
      case 1: cp = kvB1; ld = 256; cb = 0; crowbase = 0; break;
      case 2: cp = kvB1; ld = 256; cb = 128; crowbase = 0; break;
      case 3: cp = kvB2; ld = 256; cb = 0; crowbase = 0; break;
      default: cp = kvB2; ld = 256; cb = 128; crowbase = 0; break;
    }
  } else {
    switch (y) {
      case 0: cp = q_all; ld = 128; cb = 0; crowbase = NC; break;
      case 1: cp = kvA; ld = 256; cb = 0; crowbase = 0; break;
      default: cp = kvA; ld = 256; cb = 128; crowbase = 0; break;
    }
  }
  const int tid = threadIdx.x, lane = tid & 63, wv = tid >> 6;
  const int l15 = lane & 15, g4 = lane >> 4, koff = g4 * 8;
  const int sr = tid >> 1, sc = (tid & 1) * 16;
  const bool rowok = (m0 + sr) < M;

  f32x4 acc[2][8];
  #pragma unroll
  for (int mi = 0; mi < 2; ++mi)
    #pragma unroll
    for (int ni = 0; ni < 8; ++ni) acc[mi][ni] = (f32x4){0.f, 0.f, 0.f, 0.f};

  auto loadA = [&](uint4 at[2], int k0) {
    at[0] = (uint4){0, 0, 0, 0};
    at[1] = (uint4){0, 0, 0, 0};
    if (rowok) {
      const u16* ap = xh_all + (size_t)(abase + m0 + sr) * 128 + k0 + sc;
      at[0] = *(const uint4*)ap;
      at[1] = *(const uint4*)(ap + 8);
    }
  };
  auto loadB = [&](uint4 bt[2], int k0) {
    const u16* bp = Bth + (size_t)(bslab * 128 + sr) * 128 + k0 + sc;
    bt[0] = *(const uint4*)bp;
    bt[1] = *(const uint4*)(bp + 8);
  };

  uint4 aT[2][2], bT[2][2];
  loadA(aT[0], 0);
  loadB(bT[0], 0);
  loadA(aT[1], 32);
  loadB(bT[1], 32);

  for (int ks = 0; ks < 4; ++ks) {
    int cur = ks & 1;
    *(uint4*)&smem[AH + sr * 40 + sc] = aT[cur][0];
    *(uint4*)&smem[AH + sr * 40 + sc + 8] = aT[cur][1];
    *(uint4*)&smem[BH + sr * 40 + sc] = bT[cur][0];
    *(uint4*)&smem[BH + sr * 40 + sc + 8] = bT[cur][1];
    __syncthreads();
    if (ks + 2 < 4) {
      loadA(aT[cur], (ks + 2) * 32);
      loadB(bT[cur], (ks + 2) * 32);
    }
    bf16x8 a_h[2];
    #pragma unroll
    for (int mi = 0; mi < 2; ++mi) {
      int row = wv * 32 + mi * 16 + l15;
      a_h[mi] = *(const bf16x8*)&smem[AH + row * 40 + koff];
    }
    #pragma unroll
    for (int ni = 0; ni < 8; ++ni) {
      int col = ni * 16 + l15;
      bf16x8 b_h = *(const bf16x8*)&smem[BH + col * 40 + koff];
      #pragma unroll
      for (int mi = 0; mi < 2; ++mi)
        acc[mi][ni] = __builtin_amdgcn_mfma_f32_16x16x32_bf16(a_h[mi], b_h, acc[mi][ni], 0, 0, 0);
    }
    __syncthreads();
  }

  // staged epilogue: two row-halves (rows 0-63: wv 0,1; rows 64-127: wv 2,3)
  const int wrow = tid >> 2, wseg = tid & 3;
  #pragma unroll
  for (int h = 0; h < 2; ++h) {
    if (h) __syncthreads();
    if ((wv >> 1) == h) {
      #pragma unroll
      for (int mi = 0; mi < 2; ++mi) {
        int rl = (wv & 1) * 32 + mi * 16 + g4 * 4;
        #pragma unroll
        for (int ni = 0; ni < 8; ++ni) {
          float bi = biasBuf[bslab * 128 + ni * 16 + l15];
          #pragma unroll
          for (int rr = 0; rr < 4; ++rr)
            smem[(rl + rr) * 136 + ni * 16 + l15] = bf16_rne(acc[mi][ni][rr] + bi);
        }
      }
    }
    __syncthreads();
    int grow = m0 + h * 64 + wrow;
    if (grow < M) {
      uint4* dst = (uint4*)&cp[(size_t)(crowbase + grow) * ld + cb + wseg * 32];
      const uint4* src = (const uint4*)&smem[wrow * 136 + wseg * 32];
      #pragma unroll
      for (int j = 0; j < 4; ++j) dst[j] = src[j];
    }
  }
}

// ---------------- attention: pair-per-wave, 8 elems/lane, direct exp2 softmax ----------------
__device__ __forceinline__ void attn_seg(
    const u16* __restrict__ kv, int start, int end,
    const int* __restrict__ srcs, const float q8[8], int lane, float accO[8]) {
  if (start >= end) return;
  float sum = 0.0f;
  float acc[8];
  #pragma unroll
  for (int i = 0; i < 8; ++i) acc[i] = 0.0f;
  const int half = lane >> 5;
  const int sub = lane & 31;
  const int bsrc = lane & 44;  // k-lane of this head in this half
  #pragma unroll 2
  for (int e = start; e < end; e += 2) {
    int ee = e + half;
    bool valid = ee < end;
    int cl = valid ? ee : end - 1;
    int s = srcs[cl];
    uint4 u = *(const uint4*)&kv[(size_t)s * 256 + sub * 8];
    float r[8];
    r[0] = bf16_to_f((u16)(u.x & 0xffffu)); r[1] = bf16_to_f((u16)(u.x >> 16));
    r[2] = bf16_to_f((u16)(u.y & 0xffffu)); r[3] = bf16_to_f((u16)(u.y >> 16));
    r[4] = bf16_to_f((u16)(u.z & 0xffffu)); r[5] = bf16_to_f((u16)(u.z >> 16));
    r[6] = bf16_to_f((u16)(u.w & 0xffffu)); r[7] = bf16_to_f((u16)(u.w >> 16));
    float p = q8[0] * r[0];
    #pragma unroll
    for (int i = 1; i < 8; ++i) p = fmaf(q8[i], r[i], p);
    p += __shfl_xor(p, 1);
    p += __shfl_xor(p, 2);
    p = fminf(p, 100.0f);
    float w = valid ? exp2f(p) : 0.0f;
    float wB = __shfl(w, bsrc);
    sum += wB;
    #pragma unroll
    for (int i = 0; i < 8; ++i) acc[i] = fmaf(wB, r[i], acc[i]);
  }
  sum += __shfl_xor(sum, 32);
  #pragma unroll
  for (int i = 0; i < 8; ++i) acc[i] += __shfl_xor(acc[i], 32);
  float inv = 1.0f / (sum + 1e-16f);
  #pragma unroll
  for (int i = 0; i < 8; ++i) accO[i] = fmaf(acc[i], inv, accO[i]);
}

__global__ __launch_bounds__(256) void attn_all(
    const u16* __restrict__ q_all, const u16* __restrict__ kvA,
    const u16* __restrict__ kvB1, const u16* __restrict__ kvB2,
    const int* __restrict__ ptr_all, const int* __restrict__ srcs_all,
    float* __restrict__ agg_all) {
  int wave = threadIdx.x >> 6, lane = threadIdx.x & 63;
  int node = blockIdx.x * 4 + wave;
  if (node >= NTOT2) return;
  int sub = lane & 31;
  float q8[8];
  #pragma unroll
  for (int i = 0; i < 8; ++i) q8[i] = 0.0f;
  if (sub < 16) {
    uint4 u = *(const uint4*)&q_all[(size_t)node * 128 + sub * 8];
    q8[0] = bf16_to_f((u16)(u.x & 0xffffu)) * LOG2E; q8[1] = bf16_to_f((u16)(u.x >> 16)) * LOG2E;
    q8[2] = bf16_to_f((u16)(u.y & 0xffffu)) * LOG2E; q8[3] = bf16_to_f((u16)(u.y >> 16)) * LOG2E;
    q8[4] = bf16_to_f((u16)(u.z & 0xffffu)) * LOG2E; q8[5] = bf16_to_f((u16)(u.z >> 16)) * LOG2E;
    q8[6] = bf16_to_f((u16)(u.w & 0xffffu)) * LOG2E; q8[7] = bf16_to_f((u16)(u.w >> 16)) * LOG2E;
  }
  float accO[8];
  #pragma unroll
  for (int i = 0; i < 8; ++i) accO[i] = 0.0f;
  if (node < NC) {
    attn_seg(kvA, ptr_all[node], ptr_all[node + 1], srcs_all, q8, lane, accO);
    attn_seg(kvB1, ptr_all[NC + node], ptr_all[NC + node + 1], srcs_all, q8, lane, accO);
  } else {
    int idx = 2 * NC + (node - NC);
    attn_seg(kvB2, ptr_all[idx], ptr_all[idx + 1], srcs_all, q8, lane, accO);
  }
  if (lane >= 16 && lane < 32) {
    int j = lane - 16;
    float4 o0 = {accO[0], accO[1], accO[2], accO[3]};
    float4 o1 = {accO[4], accO[5], accO[6], accO[7]};
    *(float4*)&agg_all[(size_t)node * 128 + j * 8] = o0;
    *(float4*)&agg_all[(size_t)node * 128 + j * 8 + 4] = o1;
  }
}

// ---------------- final projection ----------------
__global__ __launch_bounds__(256) void gemm_out(const u16* __restrict__ Xh,
                                                const u16* __restrict__ Xl,
                                                const float* __restrict__ W,
                                                const float* __restrict__ b,
                                                float* __restrict__ out, int M) {
  __shared__ float Ws[1024];
  __shared__ float As[32][129];
  int tid = threadIdx.x;
  int m0 = blockIdx.x * 32;
  *(float4*)&Ws[tid * 4] = *(const float4*)&W[tid * 4];
  {
    int r = tid >> 3;
    int c0 = (tid & 7) * 16;
    if (m0 + r < M) {
      const u16* hp = Xh + (size_t)(m0 + r) * 128 + c0;
      const u16* lp = Xl + (size_t)(m0 + r) * 128 + c0;
      #pragma unroll
      for (int j = 0; j < 16; ++j) As[r][c0 + j] = bf16_to_f(hp[j]) + bf16_to_f(lp[j]);
    } else {
      #pragma unroll
      for (int j = 0; j < 16; ++j) As[r][c0 + j] = 0.0f;
    }
  }
  __syncthreads();
  int r = tid >> 3, c = tid & 7;
  float sum = b[c];
  #pragma unroll 16
  for (int k = 0; k < 128; ++k) sum = fmaf(As[r][k], Ws[k * 8 + c], sum);
  if (m0 + r < M) out[(size_t)(m0 + r) * 8 + c] = sum;
}

// ---------------- host orchestration ----------------
static inline size_t align256(size_t x) { return (x + 255) & ~(size_t)255; }

extern "C" void kernel_launch(void* const* d_in, const int* in_sizes, int n_in,
                              void* d_out, int out_size, void* d_ws, size_t ws_size,
                              hipStream_t stream) {
  const float* x_context = (const float*)d_in[0];
  const float* x_question = (const float*)d_in[1];
  const int* src_q2c = (const int*)d_in[2];
  const int* dst_q2c = (const int*)d_in[3];
  const int* src_c2c = (const int*)d_in[4];
  const int* dst_c2c = (const int*)d_in[5];
  const int* src_c2q = (const int*)d_in[6];
  const int* dst_c2q = (const int*)d_in[7];
  const float* inWc = (const float*)d_in[8];
  const float* inbc = (const float*)d_in[9];
  const float* inWq = (const float*)d_in[10];
  const float* inbq = (const float*)d_in[11];
  const float* kW = (const float*)d_in[12];
  const float* kB = (const float*)d_in[13];
  const float* qW = (const float*)d_in[14];
  const float* qB = (const float*)d_in[15];
  const float* vW = (const float*)d_in[16];
  const float* vB = (const float*)d_in[17];
  const float* aW = (const float*)d_in[18];
  const float* aB = (const float*)d_in[19];
  const float* skip = (const float*)d_in[20];
  const float* arel = (const float*)d_in[21];
  const float* mrel = (const float*)d_in[22];
  const float* prel = (const float*)d_in[23];
  const float* outW = (const float*)d_in[24];
  const float* outb = (const float*)d_in[25];

  char* base = (char*)d_ws;
  size_t off = 0;
  auto carve = [&](size_t bytes) -> void* {
    void* p = base + off;
    off = align256(off + bytes);
    return p;
  };
  u16* xh_all = (u16*)carve((size_t)NTOT2 * 128 * 2);
  u16* xl_all = (u16*)carve((size_t)NTOT2 * 128 * 2);
  u16* q_all = (u16*)carve((size_t)NTOT2 * 128 * 2);
  u16* kvA = (u16*)carve((size_t)NQ * 256 * 2);
  u16* kvB1 = (u16*)carve((size_t)NC * 256 * 2);
  u16* kvB2 = (u16*)carve((size_t)NC * 256 * 2);
  float* agg_all = (float*)carve((size_t)NTOT2 * 128 * 4);
  u16* Bth = (u16*)carve((size_t)2560 * 128 * 2);   // 20 slabs (both layers)
  u16* Btl = (u16*)carve((size_t)2560 * 128 * 2);
  u16* BthI = (u16*)carve((size_t)(320 + 768) * 128 * 2);
  u16* BtlI = (u16*)carve((size_t)(320 + 768) * 128 * 2);
  float* biasBuf = (float*)carve(2560 * 4);
  float* biasIn = (float*)carve(256 * 4);
  int* ptr_all = (int*)carve((size_t)(NTOT + 1) * 4);
  int* srcs_all = (int*)carve((size_t)3 * NEDGE * 4);
  int* counts = (int*)carve((size_t)NTOT * 4);
  int* cursor = (int*)carve((size_t)NTOT * 4);
  int* blksums = (int*)carve(2048 * 4);

  // ---- fused CSR build ----
  {
    int nb = (NTOT + 255) / 256;
    hipMemsetAsync(counts, 0, (size_t)NTOT * 4, stream);
    k_count3<<<(3 * NEDGE + 255) / 256, 256, 0, stream>>>(dst_q2c, dst_c2c, dst_c2q, counts);
    k_scan_block<<<nb, 256, 0, stream>>>(counts, ptr_all, blksums, NTOT);
    k_scan_sums<<<1, 1024, 0, stream>>>(blksums, nb);
    k_scan_add<<<nb, 256, 0, stream>>>(ptr_all, blksums, cursor, NTOT, 3 * NEDGE);
    k_scatter3<<<(3 * NEDGE + 255) / 256, 256, 0, stream>>>(
        src_q2c, src_c2c, src_c2q, dst_q2c, dst_c2c, dst_c2q, cursor, srcs_all);
  }

  // ---- weight prep (input + both layers) ----
  split_in<<<dim3(128, 2), 256, 0, stream>>>(inWc, inbc, inWq, inbq, BthI, BtlI, biasIn);
  prep_all<<<dim3(128, 20), 128, 0, stream>>>(kW, kB, qW, qB, vW, vB, aW, aB,
                                              arel, mrel, prel, Bth, Btl, biasBuf);

  // ---- input projections (pipelined) ----
  pipe_gemm<1><<<NBALL64, 256, 0, stream>>>(x_context, x_question, BthI, BtlI, biasIn,
                                            xh_all, xl_all, nullptr, 0);

  for (int l = 0; l < 2; ++l) {
    const u16* BthL = Bth + (size_t)l * 10 * 128 * 128;
    const u16* BtlL = Btl + (size_t)l * 10 * 128 * 128;
    const float* biasL = biasBuf + (size_t)l * 1280;
    proj_all<<<dim3(NBALL, 5), 256, 0, stream>>>(xh_all, BthL, biasL,
                                                 q_all, kvA, kvB1, kvB2);
    attn_all<<<(NTOT2 + 3) / 4, 256, 0, stream>>>(q_all, kvA, kvB1, kvB2,
                                                  ptr_all, srcs_all, agg_all);
    pipe_gemm<2><<<NBALL64, 256, 0, stream>>>(agg_all, nullptr, BthL, BtlL, biasL,
                                              xh_all, xl_all, skip, l);
  }

  gemm_out<<<(NC + 31) / 32, 256, 0, stream>>>(xh_all, xl_all, outW, outb, (float*)d_out, NC);
}

// Round 10
// 979.125 us; speedup vs baseline: 1.1507x; 1.1507x over previous
//
#include <hip/hip_runtime.h>

constexpr int NC = 100000;
constexpr int NQ = 20000;
constexpr int FC = 300;
constexpr int FQ = 768;
constexpr int NEDGE = 400000;
constexpr int NTOT = NC + NC + NQ;   // concatenated dst segments: et0 | et1 | et2
constexpr int NTOT2 = NC + NQ;       // all nodes (context then question)
constexpr int NB0 = (NC + 127) / 128;  // 782
constexpr int NB1 = (NQ + 127) / 128;  // 157
constexpr int NBALL = NB0 + NB1;       // 939
constexpr int NBC64 = (NC + 63) / 64;  // 1563
constexpr int NBQ64 = (NQ + 63) / 64;  // 313
constexpr int NBALL64 = NBC64 + NBQ64; // 1876
constexpr float SCALE = 0.17677669529663687f;  // 1/sqrt(32)
constexpr float LOG2E = 1.4426950408889634f;

typedef __attribute__((ext_vector_type(8))) short bf16x8;
typedef __attribute__((ext_vector_type(4))) float f32x4;
typedef unsigned short u16;

__device__ __forceinline__ float gelu_f(float x) {
  return 0.5f * x * (1.0f + erff(x * 0.7071067811865476f));
}
__device__ __forceinline__ u16 bf16_rne(float x) {
  unsigned u = __float_as_uint(x);
  unsigned r = u + 0x7fffu + ((u >> 16) & 1u);
  return (u16)(r >> 16);
}
__device__ __forceinline__ float bf16_to_f(u16 h) {
  return __uint_as_float(((unsigned)h) << 16);
}
__device__ __forceinline__ void split2(float x, u16& hi, u16& lo) {
  hi = bf16_rne(x);
  lo = bf16_rne(x - bf16_to_f(hi));
}
__device__ __forceinline__ void splitT(float x, u16& hi, u16& lo) {
  hi = (u16)(__float_as_uint(x) >> 16);
  lo = bf16_rne(x - bf16_to_f(hi));
}

// ---------------- fused CSR build over 3 edge types ----------------
__global__ void k_count3(const int* __restrict__ d0, const int* __restrict__ d1,
                         const int* __restrict__ d2, int* __restrict__ counts) {
  int i = blockIdx.x * 256 + threadIdx.x;
  if (i >= 3 * NEDGE) return;
  int et = i / NEDGE, e = i - et * NEDGE;
  int d = (et == 0) ? d0[e] : (et == 1) ? d1[e] : d2[e];
  int base = (et == 0) ? 0 : (et == 1) ? NC : 2 * NC;
  atomicAdd(&counts[base + d], 1);
}

__global__ void k_scan_block(const int* __restrict__ in, int* __restrict__ out,
                             int* __restrict__ bsum, int n) {
  __shared__ int s[256];
  int tid = threadIdx.x;
  int i = blockIdx.x * 256 + tid;
  int v = (i < n) ? in[i] : 0;
  s[tid] = v;
  __syncthreads();
  for (int off = 1; off < 256; off <<= 1) {
    int t = (tid >= off) ? s[tid - off] : 0;
    __syncthreads();
    s[tid] += t;
    __syncthreads();
  }
  if (i < n) out[i] = s[tid] - v;
  if (tid == 255) bsum[blockIdx.x] = s[255];
}

__global__ void k_scan_sums(int* __restrict__ bsum, int nb) {
  __shared__ int s[1024];
  int tid = threadIdx.x;
  int v = (tid < nb) ? bsum[tid] : 0;
  s[tid] = v;
  __syncthreads();
  for (int off = 1; off < 1024; off <<= 1) {
    int t = (tid >= off) ? s[tid - off] : 0;
    __syncthreads();
    s[tid] += t;
    __syncthreads();
  }
  if (tid < nb) bsum[tid] = s[tid] - v;
}

__global__ void k_scan_add(int* __restrict__ ptr, const int* __restrict__ bsum,
                           int* __restrict__ cursor, int n, int total) {
  int i = blockIdx.x * 256 + threadIdx.x;
  if (i < n) {
    int v = ptr[i] + bsum[blockIdx.x];
    ptr[i] = v;
    cursor[i] = v;
  }
  if (i == 0) ptr[n] = total;
}

__global__ void k_scatter3(const int* __restrict__ s0, const int* __restrict__ s1,
                           const int* __restrict__ s2, const int* __restrict__ d0,
                           const int* __restrict__ d1, const int* __restrict__ d2,
                           int* __restrict__ cursor, int* __restrict__ srcs_out) {
  int i = blockIdx.x * 256 + threadIdx.x;
  if (i >= 3 * NEDGE) return;
  int et = i / NEDGE, e = i - et * NEDGE;
  int d = (et == 0) ? d0[e] : (et == 1) ? d1[e] : d2[e];
  int sv = (et == 0) ? s0[e] : (et == 1) ? s1[e] : s2[e];
  int base = (et == 0) ? 0 : (et == 1) ? NC : 2 * NC;
  int p = atomicAdd(&cursor[base + d], 1);
  srcs_out[p] = sv;
}

// ---------------- B prep for BOTH layers: 20 slabs, Kp=128 ----------------
__global__ void prep_all(const float* __restrict__ kW, const float* __restrict__ kB,
                         const float* __restrict__ qW, const float* __restrict__ qB,
                         const float* __restrict__ vW, const float* __restrict__ vB,
                         const float* __restrict__ aW, const float* __restrict__ aB,
                         const float* __restrict__ arel, const float* __restrict__ mrel,
                         const float* __restrict__ prel,
                         u16* __restrict__ Bth, u16* __restrict__ Btl,
                         float* __restrict__ biasOut) {
  int i = blockIdx.x;     // input dim 0..127
  int col = threadIdx.x;  // output col 0..127
  int y = blockIdx.y;     // 0..19
  int l = y / 10, yy = y % 10;
  size_t lw = (size_t)l * 2 * 16384, lb = (size_t)l * 2 * 128;
  size_t le = (size_t)l * 3 * 4096, lp = (size_t)l * 3 * 4;
  const float *W = nullptr, *bb = nullptr, *rel = nullptr, *pr = nullptr;
  float mscale = 1.0f;
  bool fold = false;
  switch (yy) {
    case 0: W = qW + lw; bb = qB + lb; break;
    case 1: fold = true; W = kW + lw; bb = kB + lb; rel = arel + le + 4096; pr = prel + lp + 4; mscale = SCALE; break;
    case 2: fold = true; W = vW + lw; bb = vB + lb; rel = mrel + le + 4096; break;
    case 3: fold = true; W = kW + lw; bb = kB + lb; rel = arel + le + 8192; pr = prel + lp + 8; mscale = SCALE; break;
    case 4: fold = true; W = vW + lw; bb = vB + lb; rel = mrel + le + 8192; break;
    case 5: W = qW + lw + 16384; bb = qB + lb + 128; break;
    case 6: fold = true; W = kW + lw + 16384; bb = kB + lb + 128; rel = arel + le; pr = prel + lp; mscale = SCALE; break;
    case 7: fold = true; W = vW + lw + 16384; bb = vB + lb + 128; rel = mrel + le; break;
    case 8: W = aW + lw; bb = aB + lb; break;
    default: W = aW + lw + 16384; bb = aB + lb + 128; break;
  }
  int colOff = y * 128;
  if (!fold) {
    float v = W[i * 128 + col];
    u16 hi, lo;
    split2(v, hi, lo);
    Bth[(size_t)(colOff + col) * 128 + i] = hi;
    Btl[(size_t)(colOff + col) * 128 + i] = lo;
    if (i == 0) biasOut[colOff + col] = bb[col];
    return;
  }
  int h = col >> 5, f = col & 31;
  float m = (pr ? pr[h] : 1.0f) * mscale;
  float s = 0.0f;
  #pragma unroll
  for (int d = 0; d < 32; ++d)
    s += W[i * 128 + h * 32 + d] * rel[(h * 32 + d) * 32 + f];
  s *= m;
  u16 hi, lo;
  split2(s, hi, lo);
  Bth[(size_t)(colOff + col) * 128 + i] = hi;
  Btl[(size_t)(colOff + col) * 128 + i] = lo;
  if (i == 0) {
    float sb = 0.0f;
    #pragma unroll
    for (int d = 0; d < 32; ++d)
      sb += bb[h * 32 + d] * rel[(h * 32 + d) * 32 + f];
    biasOut[colOff + col] = sb * m;
  }
}

// ---------------- input weight split: y=0 context (K=300,Kp=320), y=1 question (768,768) ----
__global__ void split_in(const float* __restrict__ Wc, const float* __restrict__ bc,
                         const float* __restrict__ Wq, const float* __restrict__ bq,
                         u16* __restrict__ Bth, u16* __restrict__ Btl,
                         float* __restrict__ biasOut) {
  int n = blockIdx.x, y = blockIdx.y;
  const float* W = y ? Wq : Wc;
  const float* b = y ? bq : bc;
  int K = y ? FQ : FC, Kp = y ? 768 : 320;
  size_t boff = y ? (size_t)128 * 320 : 0;
  for (int k = threadIdx.x; k < Kp; k += 256) {
    float v = (k < K) ? W[(size_t)k * 128 + n] : 0.0f;
    u16 hi, lo;
    split2(v, hi, lo);
    Bth[boff + (size_t)n * Kp + k] = hi;
    Btl[boff + (size_t)n * Kp + k] = lo;
  }
  if (threadIdx.x == 0) biasOut[(y ? 128 : 0) + n] = b[n];
}

// ---------------- pipelined f32-A GEMM, BM=64, 3-term split, A 2-deep / B 1-deep ------------
// MODE 1: input projections (relu)  MODE 2: a-projection (gelu on A; skip-gate)
template <int MODE>
__global__ __launch_bounds__(256) void pipe_gemm(
    const float* __restrict__ Ac, const float* __restrict__ Aq,
    const u16* __restrict__ Bth, const u16* __restrict__ Btl,
    const float* __restrict__ biasBuf,
    u16* __restrict__ xh_all, u16* __restrict__ xl_all,
    const float* __restrict__ skip, int l) {
  __shared__ u16 smem[15360];  // Ah@0 Al@2560 Bh@5120 Bl@10240 (u16 offsets)
  constexpr int AH = 0, AL = 2560, BH = 5120, BL = 10240;
  const int tid = threadIdx.x, lane = tid & 63, wv = tid >> 6;
  const int l15 = lane & 15, g4 = lane >> 4, koff = g4 * 8;
  const int srA = tid >> 2, scA = (tid & 3) * 8;   // A: 8 f32/thread
  const int srB = tid >> 1, scB = (tid & 1) * 16;  // B: 16 u16/thread/array

  const int bid = blockIdx.x;
  const int nt = (bid < NBC64) ? 0 : 1;
  const int m0 = nt ? (bid - NBC64) * 64 : bid * 64;
  const int M = nt ? NQ : NC;
  const int rowbase = nt ? NC : 0;
  const float* A32;
  int K, Kp, biasOff;
  size_t boff, arow;
  if (MODE == 1) {
    if (nt == 0) { A32 = Ac; K = FC; Kp = 320; boff = 0; biasOff = 0; }
    else { A32 = Aq; K = FQ; Kp = 768; boff = (size_t)128 * 320; biasOff = 128; }
    arow = (size_t)(m0 + srA) * K;
  } else {
    A32 = Ac;
    K = 128; Kp = 128;
    boff = (size_t)(8 + nt) * 16384;
    biasOff = (8 + nt) * 128;
    arow = (size_t)(rowbase + m0 + srA) * 128;
  }
  const bool rowokA = (m0 + srA) < M;
  const int nk = (K + 31) / 32;

  f32x4 acc[8];
  #pragma unroll
  for (int ni = 0; ni < 8; ++ni) acc[ni] = (f32x4){0.f, 0.f, 0.f, 0.f};

  auto loadA = [&](float va[8], int k0) {
    if (rowokA && (k0 + 32 <= K)) {
      const float* ap = A32 + arow + k0 + scA;
      float4 f0 = *(const float4*)ap;
      float4 f1 = *(const float4*)(ap + 4);
      va[0] = f0.x; va[1] = f0.y; va[2] = f0.z; va[3] = f0.w;
      va[4] = f1.x; va[5] = f1.y; va[6] = f1.z; va[7] = f1.w;
    } else {
      #pragma unroll
      for (int j = 0; j < 8; ++j) {
        int kc = k0 + scA + j;
        va[j] = (rowokA && kc < K) ? A32[arow + kc] : 0.0f;
      }
    }
  };
  auto loadB = [&](uint4 bt[4], int k0) {
    const u16* bp = Bth + boff + (size_t)srB * Kp + k0 + scB;
    bt[0] = *(const uint4*)bp;
    bt[1] = *(const uint4*)(bp + 8);
    const u16* lp = Btl + boff + (size_t)srB * Kp + k0 + scB;
    bt[2] = *(const uint4*)lp;
    bt[3] = *(const uint4*)(lp + 8);
  };

  // A prefetched 2-deep (HBM stream), B 1-deep (L2-resident weights)
  float vaT[2][8];
  uint4 bT[4];
  loadA(vaT[0], 0);
  loadB(bT, 0);
  if (nk > 1) loadA(vaT[1], 32);

  for (int ks = 0; ks < nk; ++ks) {
    int cur = ks & 1;
    {
      alignas(16) u16 hv[8], lv[8];
      #pragma unroll
      for (int j = 0; j < 8; ++j) {
        float x = (MODE == 2) ? gelu_f(vaT[cur][j]) : vaT[cur][j];
        splitT(x, hv[j], lv[j]);
      }
      *(uint4*)&smem[AH + srA * 40 + scA] = *(const uint4*)hv;
      *(uint4*)&smem[AL + srA * 40 + scA] = *(const uint4*)lv;
      *(uint4*)&smem[BH + srB * 40 + scB] = bT[0];
      *(uint4*)&smem[BH + srB * 40 + scB + 8] = bT[1];
      *(uint4*)&smem[BL + srB * 40 + scB] = bT[2];
      *(uint4*)&smem[BL + srB * 40 + scB + 8] = bT[3];
    }
    __syncthreads();
    if (ks + 2 < nk) loadA(vaT[cur], (ks + 2) * 32);
    if (ks + 1 < nk) loadB(bT, (ks + 1) * 32);
    {
      int row = wv * 16 + l15;
      bf16x8 a_h = *(const bf16x8*)&smem[AH + row * 40 + koff];
      bf16x8 a_l = *(const bf16x8*)&smem[AL + row * 40 + koff];
      #pragma unroll
      for (int ni = 0; ni < 8; ++ni) {
        int col = ni * 16 + l15;
        bf16x8 b_h = *(const bf16x8*)&smem[BH + col * 40 + koff];
        bf16x8 b_l = *(const bf16x8*)&smem[BL + col * 40 + koff];
        acc[ni] = __builtin_amdgcn_mfma_f32_16x16x32_bf16(a_h, b_h, acc[ni], 0, 0, 0);
        acc[ni] = __builtin_amdgcn_mfma_f32_16x16x32_bf16(a_l, b_h, acc[ni], 0, 0, 0);
        acc[ni] = __builtin_amdgcn_mfma_f32_16x16x32_bf16(a_h, b_l, acc[ni], 0, 0, 0);
      }
    }
    __syncthreads();
  }

  float g = 1.0f;
  if (MODE == 2) g = 1.0f / (1.0f + __expf(-skip[l * 2 + nt]));

  #pragma unroll
  for (int ni = 0; ni < 8; ++ni) {
    int colL = ni * 16 + l15;
    float bi = biasBuf[biasOff + colL];
    int rbase = m0 + wv * 16 + g4 * 4;
    #pragma unroll
    for (int rr = 0; rr < 4; ++rr) {
      int row = rbase + rr;
      if (row >= M) continue;
      size_t idx = (size_t)(rowbase + row) * 128 + colL;
      float o = acc[ni][rr] + bi;
      if (MODE == 1) {
        o = fmaxf(o, 0.0f);
      } else {
        float xo = bf16_to_f(xh_all[idx]) + bf16_to_f(xl_all[idx]);
        o = g * o + (1.0f - g) * xo;
      }
      u16 hh, ll;
      split2(o, hh, ll);
      xh_all[idx] = hh;
      xl_all[idx] = ll;
    }
  }
}

// ---------------- q/kv projection GEMM: 1-term bf16 (xh @ Bh), slab-routed C ----------------
__global__ __launch_bounds__(256) void proj_all(
    const u16* __restrict__ xh_all,
    const u16* __restrict__ Bth, const float* __restrict__ biasBuf,
    u16* __restrict__ q_all, u16* __restrict__ kvA,
    u16* __restrict__ kvB1, u16* __restrict__ kvB2) {
  int bid = blockIdx.x, y = blockIdx.y;
  int nt = (bid < NB0) ? 0 : 1;
  if (nt == 1 && y >= 3) return;
  __shared__ u16 Ah[128][40];
  __shared__ u16 Bh[128][40];
  int m0 = nt ? (bid - NB0) * 128 : bid * 128;
  int M = nt ? NQ : NC;
  int abase = nt ? NC : 0;
  int bslab = nt ? 5 + y : y;
  u16* cp; int ld, cb, crowbase;
  if (nt == 0) {
    switch (y) {
      case 0: cp = q_all; ld = 128; cb = 0; crowbase = 0; break;
      case 1: cp = kvB1; ld = 256; cb = 0; crowbase = 0; break;
      case 2: cp = kvB1; ld = 256; cb = 128; crowbase = 0; break;
      case 3: cp = kvB2; ld = 256; cb = 0; crowbase = 0; break;
      default: cp = kvB2; ld = 256; cb = 128; crowbase = 0; break;
    }
  } else {
    switch (y) {
      case 0: cp = q_all; ld = 128; cb = 0; crowbase = NC; break;
      case 1: cp = kvA; ld = 256; cb = 0; crowbase = 0; break;
      default: cp = kvA; ld = 256; cb = 128; crowbase = 0; break;
    }
  }
  const int tid = threadIdx.x, lane = tid & 63, wv = tid >> 6;
  const int l15 = lane & 15, g4 = lane >> 4, koff = g4 * 8;
  const int sr = tid >> 1, sc = (tid & 1) * 16;
  const bool rowok = (m0 + sr) < M;

  f32x4 acc[2][8];
  #pragma unroll
  for (int mi = 0; mi < 2; ++mi)
    #pragma unroll
    for (int ni = 0; ni < 8; ++ni) acc[mi][ni] = (f32x4){0.f, 0.f, 0.f, 0.f};

  for (int k0 = 0; k0 < 128; k0 += 32) {
    uint4 h0 = {0, 0, 0, 0}, h1 = {0, 0, 0, 0};
    if (rowok) {
      const u16* ap = xh_all + (size_t)(abase + m0 + sr) * 128 + k0 + sc;
      h0 = *(const uint4*)ap;
      h1 = *(const uint4*)(ap + 8);
    }
    *(uint4*)&Ah[sr][sc] = h0;
    *(uint4*)&Ah[sr][sc + 8] = h1;
    {
      const u16* bp = Bth + (size_t)(bslab * 128 + sr) * 128 + k0 + sc;
      *(uint4*)&Bh[sr][sc] = *(const uint4*)bp;
      *(uint4*)&Bh[sr][sc + 8] = *(const uint4*)(bp + 8);
    }
    __syncthreads();

    bf16x8 a_h[2];
    #pragma unroll
    for (int mi = 0; mi < 2; ++mi) {
      int row = wv * 32 + mi * 16 + l15;
      a_h[mi] = *(const bf16x8*)&Ah[row][koff];
    }
    #pragma unroll
    for (int ni = 0; ni < 8; ++ni) {
      int col = ni * 16 + l15;
      bf16x8 b_h = *(const bf16x8*)&Bh[col][koff];
      #pragma unroll
      for (int mi = 0; mi < 2; ++mi)
        acc[mi][ni] = __builtin_amdgcn_mfma_f32_16x16x32_bf16(a_h[mi], b_h, acc[mi][ni], 0, 0, 0);
    }
    __syncthreads();
  }

  #pragma unroll
  for (int mi = 0; mi < 2; ++mi) {
    #pragma unroll
    for (int ni = 0; ni < 8; ++ni) {
      int colL = ni * 16 + l15;
      float bi = biasBuf[bslab * 128 + colL];
      int rbase = m0 + wv * 32 + mi * 16 + g4 * 4;
      #pragma unroll
      for (int rr = 0; rr < 4; ++rr) {
        int row = rbase + rr;
        if (row >= M) continue;
        float o = acc[mi][ni][rr] + bi;
        cp[(size_t)(crowbase + row) * ld + cb + colL] = bf16_rne(o);
      }
    }
  }
}

// ---------------- attention: pair-per-wave, 8 elems/lane, direct exp2 softmax ----------------
__device__ __forceinline__ void attn_seg(
    const u16* __restrict__ kv, int start, int end,
    const int* __restrict__ srcs, const float q8[8], int lane, float accO[8]) {
  if (start >= end) return;
  float sum = 0.0f;
  float acc[8];
  #pragma unroll
  for (int i = 0; i < 8; ++i) acc[i] = 0.0f;
  const int half = lane >> 5;
  const int sub = lane & 31;
  const int bsrc = lane & 44;  // k-lane of this head in this half
  #pragma unroll 2
  for (int e = start; e < end; e += 2) {
    int ee = e + half;
    bool valid = ee < end;
    int cl = valid ? ee : end - 1;
    int s = srcs[cl];
    uint4 u = *(const uint4*)&kv[(size_t)s * 256 + sub * 8];
    float r[8];
    r[0] = bf16_to_f((u16)(u.x & 0xffffu)); r[1] = bf16_to_f((u16)(u.x >> 16));
    r[2] = bf16_to_f((u16)(u.y & 0xffffu)); r[3] = bf16_to_f((u16)(u.y >> 16));
    r[4] = bf16_to_f((u16)(u.z & 0xffffu)); r[5] = bf16_to_f((u16)(u.z >> 16));
    r[6] = bf16_to_f((u16)(u.w & 0xffffu)); r[7] = bf16_to_f((u16)(u.w >> 16));
    float p = q8[0] * r[0];
    #pragma unroll
    for (int i = 1; i < 8; ++i) p = fmaf(q8[i], r[i], p);
    p += __shfl_xor(p, 1);
    p += __shfl_xor(p, 2);
    p = fminf(p, 100.0f);
    float w = valid ? exp2f(p) : 0.0f;
    float wB = __shfl(w, bsrc);
    sum += wB;
    #pragma unroll
    for (int i = 0; i < 8; ++i) acc[i] = fmaf(wB, r[i], acc[i]);
  }
  sum += __shfl_xor(sum, 32);
  #pragma unroll
  for (int i = 0; i < 8; ++i) acc[i] += __shfl_xor(acc[i], 32);
  float inv = 1.0f / (sum + 1e-16f);
  #pragma unroll
  for (int i = 0; i < 8; ++i) accO[i] = fmaf(acc[i], inv, accO[i]);
}

__global__ __launch_bounds__(256) void attn_all(
    const u16* __restrict__ q_all, const u16* __restrict__ kvA,
    const u16* __restrict__ kvB1, const u16* __restrict__ kvB2,
    const int* __restrict__ ptr_all, const int* __restrict__ srcs_all,
    float* __restrict__ agg_all) {
  int wave = threadIdx.x >> 6, lane = threadIdx.x & 63;
  int node = blockIdx.x * 4 + wave;
  if (node >= NTOT2) return;
  int sub = lane & 31;
  float q8[8];
  #pragma unroll
  for (int i = 0; i < 8; ++i) q8[i] = 0.0f;
  if (sub < 16) {
    uint4 u = *(const uint4*)&q_all[(size_t)node * 128 + sub * 8];
    q8[0] = bf16_to_f((u16)(u.x & 0xffffu)) * LOG2E; q8[1] = bf16_to_f((u16)(u.x >> 16)) * LOG2E;
    q8[2] = bf16_to_f((u16)(u.y & 0xffffu)) * LOG2E; q8[3] = bf16_to_f((u16)(u.y >> 16)) * LOG2E;
    q8[4] = bf16_to_f((u16)(u.z & 0xffffu)) * LOG2E; q8[5] = bf16_to_f((u16)(u.z >> 16)) * LOG2E;
    q8[6] = bf16_to_f((u16)(u.w & 0xffffu)) * LOG2E; q8[7] = bf16_to_f((u16)(u.w >> 16)) * LOG2E;
  }
  float accO[8];
  #pragma unroll
  for (int i = 0; i < 8; ++i) accO[i] = 0.0f;
  if (node < NC) {
    attn_seg(kvA, ptr_all[node], ptr_all[node + 1], srcs_all, q8, lane, accO);
    attn_seg(kvB1, ptr_all[NC + node], ptr_all[NC + node + 1], srcs_all, q8, lane, accO);
  } else {
    int idx = 2 * NC + (node - NC);
    attn_seg(kvB2, ptr_all[idx], ptr_all[idx + 1], srcs_all, q8, lane, accO);
  }
  if (lane >= 16 && lane < 32) {
    int j = lane - 16;
    float4 o0 = {accO[0], accO[1], accO[2], accO[3]};
    float4 o1 = {accO[4], accO[5], accO[6], accO[7]};
    *(float4*)&agg_all[(size_t)node * 128 + j * 8] = o0;
    *(float4*)&agg_all[(size_t)node * 128 + j * 8 + 4] = o1;
  }
}

// ---------------- final projection ----------------
__global__ __launch_bounds__(256) void gemm_out(const u16* __restrict__ Xh,
                                                const u16* __restrict__ Xl,
                                                const float* __restrict__ W,
                                                const float* __restrict__ b,
                                                float* __restrict__ out, int M) {
  __shared__ float Ws[1024];
  __shared__ float As[32][129];
  int tid = threadIdx.x;
  int m0 = blockIdx.x * 32;
  *(float4*)&Ws[tid * 4] = *(const float4*)&W[tid * 4];
  {
    int r = tid >> 3;
    int c0 = (tid & 7) * 16;
    if (m0 + r < M) {
      const u16* hp = Xh + (size_t)(m0 + r) * 128 + c0;
      const u16* lp = Xl + (size_t)(m0 + r) * 128 + c0;
      #pragma unroll
      for (int j = 0; j < 16; ++j) As[r][c0 + j] = bf16_to_f(hp[j]) + bf16_to_f(lp[j]);
    } else {
      #pragma unroll
      for (int j = 0; j < 16; ++j) As[r][c0 + j] = 0.0f;
    }
  }
  __syncthreads();
  int r = tid >> 3, c = tid & 7;
  float sum = b[c];
  #pragma unroll 16
  for (int k = 0; k < 128; ++k) sum = fmaf(As[r][k], Ws[k * 8 + c], sum);
  if (m0 + r < M) out[(size_t)(m0 + r) * 8 + c] = sum;
}

// ---------------- host orchestration ----------------
static inline size_t align256(size_t x) { return (x + 255) & ~(size_t)255; }

extern "C" void kernel_launch(void* const* d_in, const int* in_sizes, int n_in,
                              void* d_out, int out_size, void* d_ws, size_t ws_size,
                              hipStream_t stream) {
  const float* x_context = (const float*)d_in[0];
  const float* x_question = (const float*)d_in[1];
  const int* src_q2c = (const int*)d_in[2];
  const int* dst_q2c = (const int*)d_in[3];
  const int* src_c2c = (const int*)d_in[4];
  const int* dst_c2c = (const int*)d_in[5];
  const int* src_c2q = (const int*)d_in[6];
  const int* dst_c2q = (const int*)d_in[7];
  const float* inWc = (const float*)d_in[8];
  const float* inbc = (const float*)d_in[9];
  const float* inWq = (const float*)d_in[10];
  const float* inbq = (const float*)d_in[11];
  const float* kW = (const float*)d_in[12];
  const float* kB = (const float*)d_in[13];
  const float* qW = (const float*)d_in[14];
  const float* qB = (const float*)d_in[15];
  const float* vW = (const float*)d_in[16];
  const float* vB = (const float*)d_in[17];
  const float* aW = (const float*)d_in[18];
  const float* aB = (const float*)d_in[19];
  const float* skip = (const float*)d_in[20];
  const float* arel = (const float*)d_in[21];
  const float* mrel = (const float*)d_in[22];
  const float* prel = (const float*)d_in[23];
  const float* outW = (const float*)d_in[24];
  const float* outb = (const float*)d_in[25];

  char* base = (char*)d_ws;
  size_t off = 0;
  auto carve = [&](size_t bytes) -> void* {
    void* p = base + off;
    off = align256(off + bytes);
    return p;
  };
  u16* xh_all = (u16*)carve((size_t)NTOT2 * 128 * 2);
  u16* xl_all = (u16*)carve((size_t)NTOT2 * 128 * 2);
  u16* q_all = (u16*)carve((size_t)NTOT2 * 128 * 2);
  u16* kvA = (u16*)carve((size_t)NQ * 256 * 2);
  u16* kvB1 = (u16*)carve((size_t)NC * 256 * 2);
  u16* kvB2 = (u16*)carve((size_t)NC * 256 * 2);
  float* agg_all = (float*)carve((size_t)NTOT2 * 128 * 4);
  u16* Bth = (u16*)carve((size_t)2560 * 128 * 2);   // 20 slabs (both layers)
  u16* Btl = (u16*)carve((size_t)2560 * 128 * 2);
  u16* BthI = (u16*)carve((size_t)(320 + 768) * 128 * 2);
  u16* BtlI = (u16*)carve((size_t)(320 + 768) * 128 * 2);
  float* biasBuf = (float*)carve(2560 * 4);
  float* biasIn = (float*)carve(256 * 4);
  int* ptr_all = (int*)carve((size_t)(NTOT + 1) * 4);
  int* srcs_all = (int*)carve((size_t)3 * NEDGE * 4);
  int* counts = (int*)carve((size_t)NTOT * 4);
  int* cursor = (int*)carve((size_t)NTOT * 4);
  int* blksums = (int*)carve(2048 * 4);

  // ---- fused CSR build ----
  {
    int nb = (NTOT + 255) / 256;
    hipMemsetAsync(counts, 0, (size_t)NTOT * 4, stream);
    k_count3<<<(3 * NEDGE + 255) / 256, 256, 0, stream>>>(dst_q2c, dst_c2c, dst_c2q, counts);
    k_scan_block<<<nb, 256, 0, stream>>>(counts, ptr_all, blksums, NTOT);
    k_scan_sums<<<1, 1024, 0, stream>>>(blksums, nb);
    k_scan_add<<<nb, 256, 0, stream>>>(ptr_all, blksums, cursor, NTOT, 3 * NEDGE);
    k_scatter3<<<(3 * NEDGE + 255) / 256, 256, 0, stream>>>(
        src_q2c, src_c2c, src_c2q, dst_q2c, dst_c2c, dst_c2q, cursor, srcs_all);
  }

  // ---- weight prep (input + both layers) ----
  split_in<<<dim3(128, 2), 256, 0, stream>>>(inWc, inbc, inWq, inbq, BthI, BtlI, biasIn);
  prep_all<<<dim3(128, 20), 128, 0, stream>>>(kW, kB, qW, qB, vW, vB, aW, aB,
                                              arel, mrel, prel, Bth, Btl, biasBuf);

  // ---- input projections (pipelined) ----
  pipe_gemm<1><<<NBALL64, 256, 0, stream>>>(x_context, x_question, BthI, BtlI, biasIn,
                                            xh_all, xl_all, nullptr, 0);

  for (int l = 0; l < 2; ++l) {
    const u16* BthL = Bth + (size_t)l * 10 * 128 * 128;
    const u16* BtlL = Btl + (size_t)l * 10 * 128 * 128;
    const float* biasL = biasBuf + (size_t)l * 1280;
    proj_all<<<dim3(NBALL, 5), 256, 0, stream>>>(xh_all, BthL, biasL,
                                                 q_all, kvA, kvB1, kvB2);
    attn_all<<<(NTOT2 + 3) / 4, 256, 0, stream>>>(q_all, kvA, kvB1, kvB2,
                                                  ptr_all, srcs_all, agg_all);
    pipe_gemm<2><<<NBALL64, 256, 0, stream>>>(agg_all, nullptr, BthL, BtlL, biasL,
                                              xh_all, xl_all, skip, l);
  }

  gemm_out<<<(NC + 31) / 32, 256, 0, stream>>>(xh_all, xl_all, outW, outb, (float*)d_out, NC);
}

// Round 11
// 795.959 us; speedup vs baseline: 1.4155x; 1.2301x over previous
//
#include <hip/hip_runtime.h>

constexpr int NC = 100000;
constexpr int NQ = 20000;
constexpr int FC = 300;
constexpr int FQ = 768;
constexpr int NEDGE = 400000;
constexpr int NTOT = NC + NC + NQ;   // concatenated dst segments: et0 | et1 | et2
constexpr int NTOT2 = NC + NQ;       // all nodes (context then question)
constexpr int NB0 = (NC + 127) / 128;  // 782
constexpr int NB1 = (NQ + 127) / 128;  // 157
constexpr int NBALL = NB0 + NB1;       // 939
constexpr int NBC64 = (NC + 63) / 64;  // 1563
constexpr int NBQ64 = (NQ + 63) / 64;  // 313
constexpr int NBALL64 = NBC64 + NBQ64; // 1876
constexpr float SCALE = 0.17677669529663687f;  // 1/sqrt(32)
constexpr float LOG2E = 1.4426950408889634f;

typedef __attribute__((ext_vector_type(8))) short bf16x8;
typedef __attribute__((ext_vector_type(4))) float f32x4;
typedef unsigned short u16;

__device__ __forceinline__ float gelu_f(float x) {
  return 0.5f * x * (1.0f + erff(x * 0.7071067811865476f));
}
__device__ __forceinline__ u16 bf16_rne(float x) {
  unsigned u = __float_as_uint(x);
  unsigned r = u + 0x7fffu + ((u >> 16) & 1u);
  return (u16)(r >> 16);
}
__device__ __forceinline__ float bf16_to_f(u16 h) {
  return __uint_as_float(((unsigned)h) << 16);
}
__device__ __forceinline__ void split2(float x, u16& hi, u16& lo) {
  hi = bf16_rne(x);
  lo = bf16_rne(x - bf16_to_f(hi));
}
__device__ __forceinline__ void splitT(float x, u16& hi, u16& lo) {
  hi = (u16)(__float_as_uint(x) >> 16);
  lo = bf16_rne(x - bf16_to_f(hi));
}

// ---------------- fused CSR build over 3 edge types ----------------
__global__ void k_count3(const int* __restrict__ d0, const int* __restrict__ d1,
                         const int* __restrict__ d2, int* __restrict__ counts) {
  int i = blockIdx.x * 256 + threadIdx.x;
  if (i >= 3 * NEDGE) return;
  int et = i / NEDGE, e = i - et * NEDGE;
  int d = (et == 0) ? d0[e] : (et == 1) ? d1[e] : d2[e];
  int base = (et == 0) ? 0 : (et == 1) ? NC : 2 * NC;
  atomicAdd(&counts[base + d], 1);
}

__global__ void k_scan_block(const int* __restrict__ in, int* __restrict__ out,
                             int* __restrict__ bsum, int n) {
  __shared__ int s[256];
  int tid = threadIdx.x;
  int i = blockIdx.x * 256 + tid;
  int v = (i < n) ? in[i] : 0;
  s[tid] = v;
  __syncthreads();
  for (int off = 1; off < 256; off <<= 1) {
    int t = (tid >= off) ? s[tid - off] : 0;
    __syncthreads();
    s[tid] += t;
    __syncthreads();
  }
  if (i < n) out[i] = s[tid] - v;
  if (tid == 255) bsum[blockIdx.x] = s[255];
}

__global__ void k_scan_sums(int* __restrict__ bsum, int nb) {
  __shared__ int s[1024];
  int tid = threadIdx.x;
  int v = (tid < nb) ? bsum[tid] : 0;
  s[tid] = v;
  __syncthreads();
  for (int off = 1; off < 1024; off <<= 1) {
    int t = (tid >= off) ? s[tid - off] : 0;
    __syncthreads();
    s[tid] += t;
    __syncthreads();
  }
  if (tid < nb) bsum[tid] = s[tid] - v;
}

__global__ void k_scan_add(int* __restrict__ ptr, const int* __restrict__ bsum,
                           int* __restrict__ cursor, int n, int total) {
  int i = blockIdx.x * 256 + threadIdx.x;
  if (i < n) {
    int v = ptr[i] + bsum[blockIdx.x];
    ptr[i] = v;
    cursor[i] = v;
  }
  if (i == 0) ptr[n] = total;
}

__global__ void k_scatter3(const int* __restrict__ s0, const int* __restrict__ s1,
                           const int* __restrict__ s2, const int* __restrict__ d0,
                           const int* __restrict__ d1, const int* __restrict__ d2,
                           int* __restrict__ cursor, int* __restrict__ srcs_out) {
  int i = blockIdx.x * 256 + threadIdx.x;
  if (i >= 3 * NEDGE) return;
  int et = i / NEDGE, e = i - et * NEDGE;
  int d = (et == 0) ? d0[e] : (et == 1) ? d1[e] : d2[e];
  int sv = (et == 0) ? s0[e] : (et == 1) ? s1[e] : s2[e];
  int base = (et == 0) ? 0 : (et == 1) ? NC : 2 * NC;
  int p = atomicAdd(&cursor[base + d], 1);
  srcs_out[p] = sv;
}

// ---------------- B prep for BOTH layers: 20 slabs, Kp=128 ----------------
__global__ void prep_all(const float* __restrict__ kW, const float* __restrict__ kB,
                         const float* __restrict__ qW, const float* __restrict__ qB,
                         const float* __restrict__ vW, const float* __restrict__ vB,
                         const float* __restrict__ aW, const float* __restrict__ aB,
                         const float* __restrict__ arel, const float* __restrict__ mrel,
                         const float* __restrict__ prel,
                         u16* __restrict__ Bth, u16* __restrict__ Btl,
                         float* __restrict__ biasOut) {
  int i = blockIdx.x;     // input dim 0..127
  int col = threadIdx.x;  // output col 0..127
  int y = blockIdx.y;     // 0..19
  int l = y / 10, yy = y % 10;
  size_t lw = (size_t)l * 2 * 16384, lb = (size_t)l * 2 * 128;
  size_t le = (size_t)l * 3 * 4096, lp = (size_t)l * 3 * 4;
  const float *W = nullptr, *bb = nullptr, *rel = nullptr, *pr = nullptr;
  float mscale = 1.0f;
  bool fold = false;
  switch (yy) {
    case 0: W = qW + lw; bb = qB + lb; break;
    case 1: fold = true; W = kW + lw; bb = kB + lb; rel = arel + le + 4096; pr = prel + lp + 4; mscale = SCALE; break;
    case 2: fold = true; W = vW + lw; bb = vB + lb; rel = mrel + le + 4096; break;
    case 3: fold = true; W = kW + lw; bb = kB + lb; rel = arel + le + 8192; pr = prel + lp + 8; mscale = SCALE; break;
    case 4: fold = true; W = vW + lw; bb = vB + lb; rel = mrel + le + 8192; break;
    case 5: W = qW + lw + 16384; bb = qB + lb + 128; break;
    case 6: fold = true; W = kW + lw + 16384; bb = kB + lb + 128; rel = arel + le; pr = prel + lp; mscale = SCALE; break;
    case 7: fold = true; W = vW + lw + 16384; bb = vB + lb + 128; rel = mrel + le; break;
    case 8: W = aW + lw; bb = aB + lb; break;
    default: W = aW + lw + 16384; bb = aB + lb + 128; break;
  }
  int colOff = y * 128;
  if (!fold) {
    float v = W[i * 128 + col];
    u16 hi, lo;
    split2(v, hi, lo);
    Bth[(size_t)(colOff + col) * 128 + i] = hi;
    Btl[(size_t)(colOff + col) * 128 + i] = lo;
    if (i == 0) biasOut[colOff + col] = bb[col];
    return;
  }
  int h = col >> 5, f = col & 31;
  float m = (pr ? pr[h] : 1.0f) * mscale;
  float s = 0.0f;
  #pragma unroll
  for (int d = 0; d < 32; ++d)
    s += W[i * 128 + h * 32 + d] * rel[(h * 32 + d) * 32 + f];
  s *= m;
  u16 hi, lo;
  split2(s, hi, lo);
  Bth[(size_t)(colOff + col) * 128 + i] = hi;
  Btl[(size_t)(colOff + col) * 128 + i] = lo;
  if (i == 0) {
    float sb = 0.0f;
    #pragma unroll
    for (int d = 0; d < 32; ++d)
      sb += bb[h * 32 + d] * rel[(h * 32 + d) * 32 + f];
    biasOut[colOff + col] = sb * m;
  }
}

// ---------------- input weight split: y=0 context (K=300,Kp=320), y=1 question (768,768) ----
__global__ void split_in(const float* __restrict__ Wc, const float* __restrict__ bc,
                         const float* __restrict__ Wq, const float* __restrict__ bq,
                         u16* __restrict__ Bth, u16* __restrict__ Btl,
                         float* __restrict__ biasOut) {
  int n = blockIdx.x, y = blockIdx.y;
  const float* W = y ? Wq : Wc;
  const float* b = y ? bq : bc;
  int K = y ? FQ : FC, Kp = y ? 768 : 320;
  size_t boff = y ? (size_t)128 * 320 : 0;
  for (int k = threadIdx.x; k < Kp; k += 256) {
    float v = (k < K) ? W[(size_t)k * 128 + n] : 0.0f;
    u16 hi, lo;
    split2(v, hi, lo);
    Bth[boff + (size_t)n * Kp + k] = hi;
    Btl[boff + (size_t)n * Kp + k] = lo;
  }
  if (threadIdx.x == 0) biasOut[(y ? 128 : 0) + n] = b[n];
}

// ---------------- pipelined f32-A GEMM, BM=64, 3-term split, named-var 1-deep prefetch ------
// MODE 1: input projections (relu)  MODE 2: a-projection (gelu on A; skip-gate)
template <int MODE>
__global__ __launch_bounds__(256) void pipe_gemm(
    const float* __restrict__ Ac, const float* __restrict__ Aq,
    const u16* __restrict__ Bth, const u16* __restrict__ Btl,
    const float* __restrict__ biasBuf,
    u16* __restrict__ xh_all, u16* __restrict__ xl_all,
    const float* __restrict__ skip, int l) {
  __shared__ u16 smem[15360];  // Ah@0 Al@2560 Bh@5120 Bl@10240 ; epilogue reuses @0 [64][136]
  constexpr int AH = 0, AL = 2560, BH = 5120, BL = 10240;
  const int tid = threadIdx.x, lane = tid & 63, wv = tid >> 6;
  const int l15 = lane & 15, g4 = lane >> 4, koff = g4 * 8;
  const int srA = tid >> 2, scA = (tid & 3) * 8;   // A: 8 f32/thread
  const int srB = tid >> 1, scB = (tid & 1) * 16;  // B: 16 u16/thread/array

  const int bid = blockIdx.x;
  const int nt = (bid < NBC64) ? 0 : 1;
  const int m0 = nt ? (bid - NBC64) * 64 : bid * 64;
  const int M = nt ? NQ : NC;
  const int rowbase = nt ? NC : 0;
  const float* A32;
  int K, Kp, biasOff;
  size_t boff, arow;
  if (MODE == 1) {
    if (nt == 0) { A32 = Ac; K = FC; Kp = 320; boff = 0; biasOff = 0; }
    else { A32 = Aq; K = FQ; Kp = 768; boff = (size_t)128 * 320; biasOff = 128; }
    arow = (size_t)(m0 + srA) * K;
  } else {
    A32 = Ac;
    K = 128; Kp = 128;
    boff = (size_t)(8 + nt) * 16384;
    biasOff = (8 + nt) * 128;
    arow = (size_t)(rowbase + m0 + srA) * 128;
  }
  const bool rowokA = (m0 + srA) < M;
  const int nk = (K + 31) / 32;

  f32x4 acc[8];
  #pragma unroll
  for (int ni = 0; ni < 8; ++ni) acc[ni] = (f32x4){0.f, 0.f, 0.f, 0.f};

  auto loadA = [&](float va[8], int k0) {
    if (rowokA && (k0 + 32 <= K)) {
      const float* ap = A32 + arow + k0 + scA;
      float4 f0 = *(const float4*)ap;
      float4 f1 = *(const float4*)(ap + 4);
      va[0] = f0.x; va[1] = f0.y; va[2] = f0.z; va[3] = f0.w;
      va[4] = f1.x; va[5] = f1.y; va[6] = f1.z; va[7] = f1.w;
    } else {
      #pragma unroll
      for (int j = 0; j < 8; ++j) {
        int kc = k0 + scA + j;
        va[j] = (rowokA && kc < K) ? A32[arow + kc] : 0.0f;
      }
    }
  };
  auto loadB = [&](uint4& bh0, uint4& bh1, uint4& bl0, uint4& bl1, int k0) {
    const u16* bp = Bth + boff + (size_t)srB * Kp + k0 + scB;
    bh0 = *(const uint4*)bp;
    bh1 = *(const uint4*)(bp + 8);
    const u16* lp = Btl + boff + (size_t)srB * Kp + k0 + scB;
    bl0 = *(const uint4*)lp;
    bl1 = *(const uint4*)(lp + 8);
  };

  float vaC[8];
  uint4 bhC0, bhC1, blC0, blC1;
  loadA(vaC, 0);
  loadB(bhC0, bhC1, blC0, blC1, 0);

  for (int ks = 0; ks < nk; ++ks) {
    // ---- stage current tile to LDS (split A here) ----
    {
      alignas(16) u16 hv[8], lv[8];
      #pragma unroll
      for (int j = 0; j < 8; ++j) {
        float x = (MODE == 2) ? gelu_f(vaC[j]) : vaC[j];
        splitT(x, hv[j], lv[j]);
      }
      *(uint4*)&smem[AH + srA * 40 + scA] = *(const uint4*)hv;
      *(uint4*)&smem[AL + srA * 40 + scA] = *(const uint4*)lv;
      *(uint4*)&smem[BH + srB * 40 + scB] = bhC0;
      *(uint4*)&smem[BH + srB * 40 + scB + 8] = bhC1;
      *(uint4*)&smem[BL + srB * 40 + scB] = blC0;
      *(uint4*)&smem[BL + srB * 40 + scB + 8] = blC1;
    }
    __syncthreads();

    // ---- issue next tile's global loads (named registers, overlap with MFMA) ----
    float vaN[8];
    uint4 bhN0, bhN1, blN0, blN1;
    const bool more = (ks + 1) < nk;
    if (more) {
      loadA(vaN, (ks + 1) * 32);
      loadB(bhN0, bhN1, blN0, blN1, (ks + 1) * 32);
    }

    // ---- MFMA on current tile ----
    {
      int row = wv * 16 + l15;
      bf16x8 a_h = *(const bf16x8*)&smem[AH + row * 40 + koff];
      bf16x8 a_l = *(const bf16x8*)&smem[AL + row * 40 + koff];
      #pragma unroll
      for (int ni = 0; ni < 8; ++ni) {
        int col = ni * 16 + l15;
        bf16x8 b_h = *(const bf16x8*)&smem[BH + col * 40 + koff];
        bf16x8 b_l = *(const bf16x8*)&smem[BL + col * 40 + koff];
        acc[ni] = __builtin_amdgcn_mfma_f32_16x16x32_bf16(a_h, b_h, acc[ni], 0, 0, 0);
        acc[ni] = __builtin_amdgcn_mfma_f32_16x16x32_bf16(a_l, b_h, acc[ni], 0, 0, 0);
        acc[ni] = __builtin_amdgcn_mfma_f32_16x16x32_bf16(a_h, b_l, acc[ni], 0, 0, 0);
      }
    }
    __syncthreads();

    if (more) {
      #pragma unroll
      for (int j = 0; j < 8; ++j) vaC[j] = vaN[j];
      bhC0 = bhN0; bhC1 = bhN1; blC0 = blN0; blC1 = blN1;
    }
  }

  float g = 1.0f;
  if (MODE == 2) g = 1.0f / (1.0f + __expf(-skip[l * 2 + nt]));

  // ---- finalize results IN PLACE into acc (no extra registers) ----
  const int rl0 = wv * 16 + g4 * 4;
  #pragma unroll
  for (int ni = 0; ni < 8; ++ni) {
    int colL = ni * 16 + l15;
    float bi = biasBuf[biasOff + colL];
    #pragma unroll
    for (int rr = 0; rr < 4; ++rr) {
      int row = m0 + rl0 + rr;
      float o = acc[ni][rr] + bi;
      if (MODE == 1) {
        o = fmaxf(o, 0.0f);
      } else if (row < M) {
        size_t idx = (size_t)(rowbase + row) * 128 + colL;
        float xo = bf16_to_f(xh_all[idx]) + bf16_to_f(xl_all[idx]);
        o = g * o + (1.0f - g) * xo;
      }
      acc[ni][rr] = o;
    }
  }

  // ---- staged coalesced epilogue: hi pass then lo pass through LDS ----
  const int wrow = tid >> 2, wseg = tid & 3;
  #pragma unroll
  for (int ph = 0; ph < 2; ++ph) {
    if (ph) __syncthreads();
    #pragma unroll
    for (int ni = 0; ni < 8; ++ni) {
      #pragma unroll
      for (int rr = 0; rr < 4; ++rr) {
        u16 hh, ll;
        split2(acc[ni][rr], hh, ll);
        smem[(rl0 + rr) * 136 + ni * 16 + l15] = ph ? ll : hh;
      }
    }
    __syncthreads();
    int grow = m0 + wrow;
    if (grow < M) {
      u16* dstp = ph ? xl_all : xh_all;
      uint4* dst = (uint4*)&dstp[(size_t)(rowbase + grow) * 128 + wseg * 32];
      const uint4* src = (const uint4*)&smem[wrow * 136 + wseg * 32];
      #pragma unroll
      for (int j = 0; j < 4; ++j) dst[j] = src[j];
    }
  }
}

// ---------------- q/kv projection GEMM: 1-term bf16 (xh @ Bh), staged coalesced epilogue ----
__global__ __launch_bounds__(256) void proj_all(
    const u16* __restrict__ xh_all,
    const u16* __restrict__ Bth, const float* __restrict__ biasBuf,
    u16* __restrict__ q_all, u16* __restrict__ kvA,
    u16* __restrict__ kvB1, u16* __restrict__ kvB2) {
  int bid = blockIdx.x, y = blockIdx.y;
  int nt = (bid < NB0) ? 0 : 1;
  if (nt == 1 && y >= 3) return;
  __shared__ u16 smem[10240];  // Ah@0 [128][40], Bh@5120 [128][40]; epilogue reuses @0 [64][136]
  constexpr int AH = 0, BH = 5120;
  int m0 = nt ? (bid - NB0) * 128 : bid * 128;
  int M = nt ? NQ : NC;
  int abase = nt ? NC : 0;
  int bslab = nt ? 5 + y : y;
  u16* cp; int ld, cb, crowbase;
  if (nt == 0) {
    switch (y) {
      case 0: cp = q_all; ld = 128; cb = 0; crowbase = 0; break;
      case 1: cp = kvB1; ld = 256; cb = 0; crowbase = 0; break;
      case 2: cp = kvB1; ld = 256; cb = 128; crowbase = 0; break;
      case 3: cp = kvB2; ld = 256; cb = 0; crowbase = 0; break;
      default: cp = kvB2; ld = 256; cb = 128; crowbase = 0; break;
    }
  } else {
    switch (y) {
      case 0: cp = q_all; ld = 128; cb = 0; crowbase = NC; break;
      case 1: cp = kvA; ld = 256; cb = 0; crowbase = 0; break;
      default: cp = kvA; ld = 256; cb = 128; crowbase = 0; break;
    }
  }
  const int tid = threadIdx.x, lane = tid & 63, wv = tid >> 6;
  const int l15 = lane & 15, g4 = lane >> 4, koff = g4 * 8;
  const int sr = tid >> 1, sc = (tid & 1) * 16;
  const bool rowok = (m0 + sr) < M;

  f32x4 acc[2][8];
  #pragma unroll
  for (int mi = 0; mi < 2; ++mi)
    #pragma unroll
    for (int ni = 0; ni < 8; ++ni) acc[mi][ni] = (f32x4){0.f, 0.f, 0.f, 0.f};

  for (int k0 = 0; k0 < 128; k0 += 32) {
    uint4 h0 = {0, 0, 0, 0}, h1 = {0, 0, 0, 0};
    if (rowok) {
      const u16* ap = xh_all + (size_t)(abase + m0 + sr) * 128 + k0 + sc;
      h0 = *(const uint4*)ap;
      h1 = *(const uint4*)(ap + 8);
    }
    *(uint4*)&smem[AH + sr * 40 + sc] = h0;
    *(uint4*)&smem[AH + sr * 40 + sc + 8] = h1;
    {
      const u16* bp = Bth + (size_t)(bslab * 128 + sr) * 128 + k0 + sc;
      *(uint4*)&smem[BH + sr * 40 + sc] = *(const uint4*)bp;
      *(uint4*)&smem[BH + sr * 40 + sc + 8] = *(const uint4*)(bp + 8);
    }
    __syncthreads();

    bf16x8 a_h[2];
    #pragma unroll
    for (int mi = 0; mi < 2; ++mi) {
      int row = wv * 32 + mi * 16 + l15;
      a_h[mi] = *(const bf16x8*)&smem[AH + row * 40 + koff];
    }
    #pragma unroll
    for (int ni = 0; ni < 8; ++ni) {
      int col = ni * 16 + l15;
      bf16x8 b_h = *(const bf16x8*)&smem[BH + col * 40 + koff];
      #pragma unroll
      for (int mi = 0; mi < 2; ++mi)
        acc[mi][ni] = __builtin_amdgcn_mfma_f32_16x16x32_bf16(a_h[mi], b_h, acc[mi][ni], 0, 0, 0);
    }
    __syncthreads();
  }

  // ---- staged coalesced epilogue: two row-halves (rows 0-63: wv 0,1; rows 64-127: wv 2,3) --
  const int wrow = tid >> 2, wseg = tid & 3;
  #pragma unroll
  for (int h = 0; h < 2; ++h) {
    if (h) __syncthreads();
    if ((wv >> 1) == h) {
      #pragma unroll
      for (int mi = 0; mi < 2; ++mi) {
        int rl = (wv & 1) * 32 + mi * 16 + g4 * 4;
        #pragma unroll
        for (int ni = 0; ni < 8; ++ni) {
          float bi = biasBuf[bslab * 128 + ni * 16 + l15];
          #pragma unroll
          for (int rr = 0; rr < 4; ++rr)
            smem[(rl + rr) * 136 + ni * 16 + l15] = bf16_rne(acc[mi][ni][rr] + bi);
        }
      }
    }
    __syncthreads();
    int grow = m0 + h * 64 + wrow;
    if (grow < M) {
      uint4* dst = (uint4*)&cp[(size_t)(crowbase + grow) * ld + cb + wseg * 32];
      const uint4* src = (const uint4*)&smem[wrow * 136 + wseg * 32];
      #pragma unroll
      for (int j = 0; j < 4; ++j) dst[j] = src[j];
    }
  }
}

// ---------------- attention: pair-per-wave, 8 elems/lane, direct exp2 softmax ----------------
__device__ __forceinline__ void attn_seg(
    const u16* __restrict__ kv, int start, int end,
    const int* __restrict__ srcs, const float q8[8], int lane, float accO[8]) {
  if (start >= end) return;
  float sum = 0.0f;
  float acc[8];
  #pragma unroll
  for (int i = 0; i < 8; ++i) acc[i] = 0.0f;
  const int half = lane >> 5;
  const int sub = lane & 31;
  const int bsrc = lane & 44;  // k-lane of this head in this half
  #pragma unroll 2
  for (int e = start; e < end; e += 2) {
    int ee = e + half;
    bool valid = ee < end;
    int cl = valid ? ee : end - 1;
    int s = srcs[cl];
    uint4 u = *(const uint4*)&kv[(size_t)s * 256 + sub * 8];
    float r[8];
    r[0] = bf16_to_f((u16)(u.x & 0xffffu)); r[1] = bf16_to_f((u16)(u.x >> 16));
    r[2] = bf16_to_f((u16)(u.y & 0xffffu)); r[3] = bf16_to_f((u16)(u.y >> 16));
    r[4] = bf16_to_f((u16)(u.z & 0xffffu)); r[5] = bf16_to_f((u16)(u.z >> 16));
    r[6] = bf16_to_f((u16)(u.w & 0xffffu)); r[7] = bf16_to_f((u16)(u.w >> 16));
    float p = q8[0] * r[0];
    #pragma unroll
    for (int i = 1; i < 8; ++i) p = fmaf(q8[i], r[i], p);
    p += __shfl_xor(p, 1);
    p += __shfl_xor(p, 2);
    p = fminf(p, 100.0f);
    float w = valid ? exp2f(p) : 0.0f;
    float wB = __shfl(w, bsrc);
    sum += wB;
    #pragma unroll
    for (int i = 0; i < 8; ++i) acc[i] = fmaf(wB, r[i], acc[i]);
  }
  sum += __shfl_xor(sum, 32);
  #pragma unroll
  for (int i = 0; i < 8; ++i) acc[i] += __shfl_xor(acc[i], 32);
  float inv = 1.0f / (sum + 1e-16f);
  #pragma unroll
  for (int i = 0; i < 8; ++i) accO[i] = fmaf(acc[i], inv, accO[i]);
}

__global__ __launch_bounds__(256) void attn_all(
    const u16* __restrict__ q_all, const u16* __restrict__ kvA,
    const u16* __restrict__ kvB1, const u16* __restrict__ kvB2,
    const int* __restrict__ ptr_all, const int* __restrict__ srcs_all,
    float* __restrict__ agg_all) {
  int wave = threadIdx.x >> 6, lane = threadIdx.x & 63;
  int node = blockIdx.x * 4 + wave;
  if (node >= NTOT2) return;
  int sub = lane & 31;
  float q8[8];
  #pragma unroll
  for (int i = 0; i < 8; ++i) q8[i] = 0.0f;
  if (sub < 16) {
    uint4 u = *(const uint4*)&q_all[(size_t)node * 128 + sub * 8];
    q8[0] = bf16_to_f((u16)(u.x & 0xffffu)) * LOG2E; q8[1] = bf16_to_f((u16)(u.x >> 16)) * LOG2E;
    q8[2] = bf16_to_f((u16)(u.y & 0xffffu)) * LOG2E; q8[3] = bf16_to_f((u16)(u.y >> 16)) * LOG2E;
    q8[4] = bf16_to_f((u16)(u.z & 0xffffu)) * LOG2E; q8[5] = bf16_to_f((u16)(u.z >> 16)) * LOG2E;
    q8[6] = bf16_to_f((u16)(u.w & 0xffffu)) * LOG2E; q8[7] = bf16_to_f((u16)(u.w >> 16)) * LOG2E;
  }
  float accO[8];
  #pragma unroll
  for (int i = 0; i < 8; ++i) accO[i] = 0.0f;
  if (node < NC) {
    attn_seg(kvA, ptr_all[node], ptr_all[node + 1], srcs_all, q8, lane, accO);
    attn_seg(kvB1, ptr_all[NC + node], ptr_all[NC + node + 1], srcs_all, q8, lane, accO);
  } else {
    int idx = 2 * NC + (node - NC);
    attn_seg(kvB2, ptr_all[idx], ptr_all[idx + 1], srcs_all, q8, lane, accO);
  }
  if (lane >= 16 && lane < 32) {
    int j = lane - 16;
    float4 o0 = {accO[0], accO[1], accO[2], accO[3]};
    float4 o1 = {accO[4], accO[5], accO[6], accO[7]};
    *(float4*)&agg_all[(size_t)node * 128 + j * 8] = o0;
    *(float4*)&agg_all[(size_t)node * 128 + j * 8 + 4] = o1;
  }
}

// ---------------- final projection ----------------
__global__ __launch_bounds__(256) void gemm_out(const u16* __restrict__ Xh,
                                                const u16* __restrict__ Xl,
                                                const float* __restrict__ W,
                                                const float* __restrict__ b,
                                                float* __restrict__ out, int M) {
  __shared__ float Ws[1024];
  __shared__ float As[32][129];
  int tid = threadIdx.x;
  int m0 = blockIdx.x * 32;
  *(float4*)&Ws[tid * 4] = *(const float4*)&W[tid * 4];
  {
    int r = tid >> 3;
    int c0 = (tid & 7) * 16;
    if (m0 + r < M) {
      const u16* hp = Xh + (size_t)(m0 + r) * 128 + c0;
      const u16* lp = Xl + (size_t)(m0 + r) * 128 + c0;
      #pragma unroll
      for (int j = 0; j < 16; ++j) As[r][c0 + j] = bf16_to_f(hp[j]) + bf16_to_f(lp[j]);
    } else {
      #pragma unroll
      for (int j = 0; j < 16; ++j) As[r][c0 + j] = 0.0f;
    }
  }
  __syncthreads();
  int r = tid >> 3, c = tid & 7;
  float sum = b[c];
  #pragma unroll 16
  for (int k = 0; k < 128; ++k) sum = fmaf(As[r][k], Ws[k * 8 + c], sum);
  if (m0 + r < M) out[(size_t)(m0 + r) * 8 + c] = sum;
}

// ---------------- host orchestration ----------------
static inline size_t align256(size_t x) { return (x + 255) & ~(size_t)255; }

extern "C" void kernel_launch(void* const* d_in, const int* in_sizes, int n_in,
                              void* d_out, int out_size, void* d_ws, size_t ws_size,
                              hipStream_t stream) {
  const float* x_context = (const float*)d_in[0];
  const float* x_question = (const float*)d_in[1];
  const int* src_q2c = (const int*)d_in[2];
  const int* dst_q2c = (const int*)d_in[3];
  const int* src_c2c = (const int*)d_in[4];
  const int* dst_c2c = (const int*)d_in[5];
  const int* src_c2q = (const int*)d_in[6];
  const int* dst_c2q = (const int*)d_in[7];
  const float* inWc = (const float*)d_in[8];
  const float* inbc = (const float*)d_in[9];
  const float* inWq = (const float*)d_in[10];
  const float* inbq = (const float*)d_in[11];
  const float* kW = (const float*)d_in[12];
  const float* kB = (const float*)d_in[13];
  const float* qW = (const float*)d_in[14];
  const float* qB = (const float*)d_in[15];
  const float* vW = (const float*)d_in[16];
  const float* vB = (const float*)d_in[17];
  const float* aW = (const float*)d_in[18];
  const float* aB = (const float*)d_in[19];
  const float* skip = (const float*)d_in[20];
  const float* arel = (const float*)d_in[21];
  const float* mrel = (const float*)d_in[22];
  const float* prel = (const float*)d_in[23];
  const float* outW = (const float*)d_in[24];
  const float* outb = (const float*)d_in[25];

  char* base = (char*)d_ws;
  size_t off = 0;
  auto carve = [&](size_t bytes) -> void* {
    void* p = base + off;
    off = align256(off + bytes);
    return p;
  };
  u16* xh_all = (u16*)carve((size_t)NTOT2 * 128 * 2);
  u16* xl_all = (u16*)carve((size_t)NTOT2 * 128 * 2);
  u16* q_all = (u16*)carve((size_t)NTOT2 * 128 * 2);
  u16* kvA = (u16*)carve((size_t)NQ * 256 * 2);
  u16* kvB1 = (u16*)carve((size_t)NC * 256 * 2);
  u16* kvB2 = (u16*)carve((size_t)NC * 256 * 2);
  float* agg_all = (float*)carve((size_t)NTOT2 * 128 * 4);
  u16* Bth = (u16*)carve((size_t)2560 * 128 * 2);   // 20 slabs (both layers)
  u16* Btl = (u16*)carve((size_t)2560 * 128 * 2);
  u16* BthI = (u16*)carve((size_t)(320 + 768) * 128 * 2);
  u16* BtlI = (u16*)carve((size_t)(320 + 768) * 128 * 2);
  float* biasBuf = (float*)carve(2560 * 4);
  float* biasIn = (float*)carve(256 * 4);
  int* ptr_all = (int*)carve((size_t)(NTOT + 1) * 4);
  int* srcs_all = (int*)carve((size_t)3 * NEDGE * 4);
  int* counts = (int*)carve((size_t)NTOT * 4);
  int* cursor = (int*)carve((size_t)NTOT * 4);
  int* blksums = (int*)carve(2048 * 4);

  // ---- fused CSR build ----
  {
    int nb = (NTOT + 255) / 256;
    hipMemsetAsync(counts, 0, (size_t)NTOT * 4, stream);
    k_count3<<<(3 * NEDGE + 255) / 256, 256, 0, stream>>>(dst_q2c, dst_c2c, dst_c2q, counts);
    k_scan_block<<<nb, 256, 0, stream>>>(counts, ptr_all, blksums, NTOT);
    k_scan_sums<<<1, 1024, 0, stream>>>(blksums, nb);
    k_scan_add<<<nb, 256, 0, stream>>>(ptr_all, blksums, cursor, NTOT, 3 * NEDGE);
    k_scatter3<<<(3 * NEDGE + 255) / 256, 256, 0, stream>>>(
        src_q2c, src_c2c, src_c2q, dst_q2c, dst_c2c, dst_c2q, cursor, srcs_all);
  }

  // ---- weight prep (input + both layers) ----
  split_in<<<dim3(128, 2), 256, 0, stream>>>(inWc, inbc, inWq, inbq, BthI, BtlI, biasIn);
  prep_all<<<dim3(128, 20), 128, 0, stream>>>(kW, kB, qW, qB, vW, vB, aW, aB,
                                              arel, mrel, prel, Bth, Btl, biasBuf);

  // ---- input projections (pipelined) ----
  pipe_gemm<1><<<NBALL64, 256, 0, stream>>>(x_context, x_question, BthI, BtlI, biasIn,
                                            xh_all, xl_all, nullptr, 0);

  for (int l = 0; l < 2; ++l) {
    const u16* BthL = Bth + (size_t)l * 10 * 128 * 128;
    const u16* BtlL = Btl + (size_t)l * 10 * 128 * 128;
    const float* biasL = biasBuf + (size_t)l * 1280;
    proj_all<<<dim3(NBALL, 5), 256, 0, stream>>>(xh_all, BthL, biasL,
                                                 q_all, kvA, kvB1, kvB2);
    attn_all<<<(NTOT2 + 3) / 4, 256, 0, stream>>>(q_all, kvA, kvB1, kvB2,
                                                  ptr_all, srcs_all, agg_all);
    pipe_gemm<2><<<NBALL64, 256, 0, stream>>>(agg_all, nullptr, BthL, BtlL, biasL,
                                              xh_all, xl_all, skip, l);
  }

  gemm_out<<<(NC + 31) / 32, 256, 0, stream>>>(xh_all, xl_all, outW, outb, (float*)d_out, NC);
}

// Round 12
// 696.224 us; speedup vs baseline: 1.6183x; 1.1433x over previous
//
#include <hip/hip_runtime.h>

constexpr int NC = 100000;
constexpr int NQ = 20000;
constexpr int FC = 300;
constexpr int FQ = 768;
constexpr int NEDGE = 400000;
constexpr int NTOT = NC + NC + NQ;   // concatenated dst segments: et0 | et1 | et2
constexpr int NTOT2 = NC + NQ;       // all nodes (context then question)
constexpr int NB0 = (NC + 127) / 128;  // 782
constexpr int NB1 = (NQ + 127) / 128;  // 157
constexpr int NBALL = NB0 + NB1;       // 939
constexpr int NBC64 = (NC + 63) / 64;  // 1563
constexpr int NBQ64 = (NQ + 63) / 64;  // 313
constexpr int NBALL64 = NBC64 + NBQ64; // 1876
constexpr float SCALE = 0.17677669529663687f;  // 1/sqrt(32)
constexpr float LOG2E = 1.4426950408889634f;

typedef __attribute__((ext_vector_type(8))) short bf16x8;
typedef __attribute__((ext_vector_type(4))) float f32x4;
typedef unsigned short u16;

__device__ __forceinline__ float gelu_f(float x) {
  return 0.5f * x * (1.0f + erff(x * 0.7071067811865476f));
}
__device__ __forceinline__ u16 bf16_rne(float x) {
  unsigned u = __float_as_uint(x);
  unsigned r = u + 0x7fffu + ((u >> 16) & 1u);
  return (u16)(r >> 16);
}
__device__ __forceinline__ float bf16_to_f(u16 h) {
  return __uint_as_float(((unsigned)h) << 16);
}
__device__ __forceinline__ void split2(float x, u16& hi, u16& lo) {
  hi = bf16_rne(x);
  lo = bf16_rne(x - bf16_to_f(hi));
}
__device__ __forceinline__ void splitT(float x, u16& hi, u16& lo) {
  hi = (u16)(__float_as_uint(x) >> 16);
  lo = bf16_rne(x - bf16_to_f(hi));
}

// ---------------- fused CSR build over 3 edge types ----------------
__global__ void k_count3(const int* __restrict__ d0, const int* __restrict__ d1,
                         const int* __restrict__ d2, int* __restrict__ counts) {
  int i = blockIdx.x * 256 + threadIdx.x;
  if (i >= 3 * NEDGE) return;
  int et = i / NEDGE, e = i - et * NEDGE;
  int d = (et == 0) ? d0[e] : (et == 1) ? d1[e] : d2[e];
  int base = (et == 0) ? 0 : (et == 1) ? NC : 2 * NC;
  atomicAdd(&counts[base + d], 1);
}

__global__ void k_scan_block(const int* __restrict__ in, int* __restrict__ out,
                             int* __restrict__ bsum, int n) {
  __shared__ int s[256];
  int tid = threadIdx.x;
  int i = blockIdx.x * 256 + tid;
  int v = (i < n) ? in[i] : 0;
  s[tid] = v;
  __syncthreads();
  for (int off = 1; off < 256; off <<= 1) {
    int t = (tid >= off) ? s[tid - off] : 0;
    __syncthreads();
    s[tid] += t;
    __syncthreads();
  }
  if (i < n) out[i] = s[tid] - v;
  if (tid == 255) bsum[blockIdx.x] = s[255];
}

__global__ void k_scan_sums(int* __restrict__ bsum, int nb) {
  __shared__ int s[1024];
  int tid = threadIdx.x;
  int v = (tid < nb) ? bsum[tid] : 0;
  s[tid] = v;
  __syncthreads();
  for (int off = 1; off < 1024; off <<= 1) {
    int t = (tid >= off) ? s[tid - off] : 0;
    __syncthreads();
    s[tid] += t;
    __syncthreads();
  }
  if (tid < nb) bsum[tid] = s[tid] - v;
}

__global__ void k_scan_add(int* __restrict__ ptr, const int* __restrict__ bsum,
                           int* __restrict__ cursor, int n, int total) {
  int i = blockIdx.x * 256 + threadIdx.x;
  if (i < n) {
    int v = ptr[i] + bsum[blockIdx.x];
    ptr[i] = v;
    cursor[i] = v;
  }
  if (i == 0) ptr[n] = total;
}

__global__ void k_scatter3(const int* __restrict__ s0, const int* __restrict__ s1,
                           const int* __restrict__ s2, const int* __restrict__ d0,
                           const int* __restrict__ d1, const int* __restrict__ d2,
                           int* __restrict__ cursor, int* __restrict__ srcs_out) {
  int i = blockIdx.x * 256 + threadIdx.x;
  if (i >= 3 * NEDGE) return;
  int et = i / NEDGE, e = i - et * NEDGE;
  int d = (et == 0) ? d0[e] : (et == 1) ? d1[e] : d2[e];
  int sv = (et == 0) ? s0[e] : (et == 1) ? s1[e] : s2[e];
  int base = (et == 0) ? 0 : (et == 1) ? NC : 2 * NC;
  int p = atomicAdd(&cursor[base + d], 1);
  srcs_out[p] = sv;
}

// ---------------- B prep for BOTH layers: 20 slabs, Kp=128 ----------------
__global__ void prep_all(const float* __restrict__ kW, const float* __restrict__ kB,
                         const float* __restrict__ qW, const float* __restrict__ qB,
                         const float* __restrict__ vW, const float* __restrict__ vB,
                         const float* __restrict__ aW, const float* __restrict__ aB,
                         const float* __restrict__ arel, const float* __restrict__ mrel,
                         const float* __restrict__ prel,
                         u16* __restrict__ Bth, u16* __restrict__ Btl,
                         float* __restrict__ biasOut) {
  int i = blockIdx.x;     // input dim 0..127
  int col = threadIdx.x;  // output col 0..127
  int y = blockIdx.y;     // 0..19
  int l = y / 10, yy = y % 10;
  size_t lw = (size_t)l * 2 * 16384, lb = (size_t)l * 2 * 128;
  size_t le = (size_t)l * 3 * 4096, lp = (size_t)l * 3 * 4;
  const float *W = nullptr, *bb = nullptr, *rel = nullptr, *pr = nullptr;
  float mscale = 1.0f;
  bool fold = false;
  switch (yy) {
    case 0: W = qW + lw; bb = qB + lb; break;
    case 1: fold = true; W = kW + lw; bb = kB + lb; rel = arel + le + 4096; pr = prel + lp + 4; mscale = SCALE; break;
    case 2: fold = true; W = vW + lw; bb = vB + lb; rel = mrel + le + 4096; break;
    case 3: fold = true; W = kW + lw; bb = kB + lb; rel = arel + le + 8192; pr = prel + lp + 8; mscale = SCALE; break;
    case 4: fold = true; W = vW + lw; bb = vB + lb; rel = mrel + le + 8192; break;
    case 5: W = qW + lw + 16384; bb = qB + lb + 128; break;
    case 6: fold = true; W = kW + lw + 16384; bb = kB + lb + 128; rel = arel + le; pr = prel + lp; mscale = SCALE; break;
    case 7: fold = true; W = vW + lw + 16384; bb = vB + lb + 128; rel = mrel + le; break;
    case 8: W = aW + lw; bb = aB + lb; break;
    default: W = aW + lw + 16384; bb = aB + lb + 128; break;
  }
  int colOff = y * 128;
  if (!fold) {
    float v = W[i * 128 + col];
    u16 hi, lo;
    split2(v, hi, lo);
    Bth[(size_t)(colOff + col) * 128 + i] = hi;
    Btl[(size_t)(colOff + col) * 128 + i] = lo;
    if (i == 0) biasOut[colOff + col] = bb[col];
    return;
  }
  int h = col >> 5, f = col & 31;
  float m = (pr ? pr[h] : 1.0f) * mscale;
  float s = 0.0f;
  #pragma unroll
  for (int d = 0; d < 32; ++d)
    s += W[i * 128 + h * 32 + d] * rel[(h * 32 + d) * 32 + f];
  s *= m;
  u16 hi, lo;
  split2(s, hi, lo);
  Bth[(size_t)(colOff + col) * 128 + i] = hi;
  Btl[(size_t)(colOff + col) * 128 + i] = lo;
  if (i == 0) {
    float sb = 0.0f;
    #pragma unroll
    for (int d = 0; d < 32; ++d)
      sb += bb[h * 32 + d] * rel[(h * 32 + d) * 32 + f];
    biasOut[colOff + col] = sb * m;
  }
}

// ---------------- input weight split: y=0 context (K=300,Kp=320), y=1 question (768,768) ----
__global__ void split_in(const float* __restrict__ Wc, const float* __restrict__ bc,
                         const float* __restrict__ Wq, const float* __restrict__ bq,
                         u16* __restrict__ Bth, u16* __restrict__ Btl,
                         float* __restrict__ biasOut) {
  int n = blockIdx.x, y = blockIdx.y;
  const float* W = y ? Wq : Wc;
  const float* b = y ? bq : bc;
  int K = y ? FQ : FC, Kp = y ? 768 : 320;
  size_t boff = y ? (size_t)128 * 320 : 0;
  for (int k = threadIdx.x; k < Kp; k += 256) {
    float v = (k < K) ? W[(size_t)k * 128 + n] : 0.0f;
    u16 hi, lo;
    split2(v, hi, lo);
    Bth[boff + (size_t)n * Kp + k] = hi;
    Btl[boff + (size_t)n * Kp + k] = lo;
  }
  if (threadIdx.x == 0) biasOut[(y ? 128 : 0) + n] = b[n];
}

// ---------------- pipelined f32-A GEMM, BM=64, 3-term split, named-var 1-deep prefetch ------
// MODE 1: input projections (relu)  MODE 2: a-projection (gelu on A; skip-gate)
template <int MODE>
__global__ __launch_bounds__(256) void pipe_gemm(
    const float* __restrict__ Ac, const float* __restrict__ Aq,
    const u16* __restrict__ Bth, const u16* __restrict__ Btl,
    const float* __restrict__ biasBuf,
    u16* __restrict__ xh_all, u16* __restrict__ xl_all,
    const float* __restrict__ skip, int l) {
  __shared__ u16 smem[15360];  // Ah@0 Al@2560 Bh@5120 Bl@10240 ; epilogue reuses @0 [64][136]
  constexpr int AH = 0, AL = 2560, BH = 5120, BL = 10240;
  const int tid = threadIdx.x, lane = tid & 63, wv = tid >> 6;
  const int l15 = lane & 15, g4 = lane >> 4, koff = g4 * 8;
  const int srA = tid >> 2, scA = (tid & 3) * 8;   // A: 8 f32/thread
  const int srB = tid >> 1, scB = (tid & 1) * 16;  // B: 16 u16/thread/array

  const int bid = blockIdx.x;
  const int nt = (bid < NBC64) ? 0 : 1;
  const int m0 = nt ? (bid - NBC64) * 64 : bid * 64;
  const int M = nt ? NQ : NC;
  const int rowbase = nt ? NC : 0;
  const float* A32;
  int K, Kp, biasOff;
  size_t boff, arow;
  if (MODE == 1) {
    if (nt == 0) { A32 = Ac; K = FC; Kp = 320; boff = 0; biasOff = 0; }
    else { A32 = Aq; K = FQ; Kp = 768; boff = (size_t)128 * 320; biasOff = 128; }
    arow = (size_t)(m0 + srA) * K;
  } else {
    A32 = Ac;
    K = 128; Kp = 128;
    boff = (size_t)(8 + nt) * 16384;
    biasOff = (8 + nt) * 128;
    arow = (size_t)(rowbase + m0 + srA) * 128;
  }
  const bool rowokA = (m0 + srA) < M;
  const int nk = (K + 31) / 32;

  f32x4 acc[8];
  #pragma unroll
  for (int ni = 0; ni < 8; ++ni) acc[ni] = (f32x4){0.f, 0.f, 0.f, 0.f};

  auto loadA = [&](float va[8], int k0) {
    if (rowokA && (k0 + 32 <= K)) {
      const float* ap = A32 + arow + k0 + scA;
      float4 f0 = *(const float4*)ap;
      float4 f1 = *(const float4*)(ap + 4);
      va[0] = f0.x; va[1] = f0.y; va[2] = f0.z; va[3] = f0.w;
      va[4] = f1.x; va[5] = f1.y; va[6] = f1.z; va[7] = f1.w;
    } else {
      #pragma unroll
      for (int j = 0; j < 8; ++j) {
        int kc = k0 + scA + j;
        va[j] = (rowokA && kc < K) ? A32[arow + kc] : 0.0f;
      }
    }
  };
  auto loadB = [&](uint4& bh0, uint4& bh1, uint4& bl0, uint4& bl1, int k0) {
    const u16* bp = Bth + boff + (size_t)srB * Kp + k0 + scB;
    bh0 = *(const uint4*)bp;
    bh1 = *(const uint4*)(bp + 8);
    const u16* lp = Btl + boff + (size_t)srB * Kp + k0 + scB;
    bl0 = *(const uint4*)lp;
    bl1 = *(const uint4*)(lp + 8);
  };

  float vaC[8];
  uint4 bhC0, bhC1, blC0, blC1;
  loadA(vaC, 0);
  loadB(bhC0, bhC1, blC0, blC1, 0);

  for (int ks = 0; ks < nk; ++ks) {
    {
      alignas(16) u16 hv[8], lv[8];
      #pragma unroll
      for (int j = 0; j < 8; ++j) {
        float x = (MODE == 2) ? gelu_f(vaC[j]) : vaC[j];
        splitT(x, hv[j], lv[j]);
      }
      *(uint4*)&smem[AH + srA * 40 + scA] = *(const uint4*)hv;
      *(uint4*)&smem[AL + srA * 40 + scA] = *(const uint4*)lv;
      *(uint4*)&smem[BH + srB * 40 + scB] = bhC0;
      *(uint4*)&smem[BH + srB * 40 + scB + 8] = bhC1;
      *(uint4*)&smem[BL + srB * 40 + scB] = blC0;
      *(uint4*)&smem[BL + srB * 40 + scB + 8] = blC1;
    }
    __syncthreads();

    float vaN[8];
    uint4 bhN0, bhN1, blN0, blN1;
    const bool more = (ks + 1) < nk;
    if (more) {
      loadA(vaN, (ks + 1) * 32);
      loadB(bhN0, bhN1, blN0, blN1, (ks + 1) * 32);
    }

    {
      int row = wv * 16 + l15;
      bf16x8 a_h = *(const bf16x8*)&smem[AH + row * 40 + koff];
      bf16x8 a_l = *(const bf16x8*)&smem[AL + row * 40 + koff];
      #pragma unroll
      for (int ni = 0; ni < 8; ++ni) {
        int col = ni * 16 + l15;
        bf16x8 b_h = *(const bf16x8*)&smem[BH + col * 40 + koff];
        bf16x8 b_l = *(const bf16x8*)&smem[BL + col * 40 + koff];
        acc[ni] = __builtin_amdgcn_mfma_f32_16x16x32_bf16(a_h, b_h, acc[ni], 0, 0, 0);
        acc[ni] = __builtin_amdgcn_mfma_f32_16x16x32_bf16(a_l, b_h, acc[ni], 0, 0, 0);
        acc[ni] = __builtin_amdgcn_mfma_f32_16x16x32_bf16(a_h, b_l, acc[ni], 0, 0, 0);
      }
    }
    __syncthreads();

    if (more) {
      #pragma unroll
      for (int j = 0; j < 8; ++j) vaC[j] = vaN[j];
      bhC0 = bhN0; bhC1 = bhN1; blC0 = blN0; blC1 = blN1;
    }
  }

  float g = 1.0f;
  if (MODE == 2) g = 1.0f / (1.0f + __expf(-skip[l * 2 + nt]));

  const int rl0 = wv * 16 + g4 * 4;
  #pragma unroll
  for (int ni = 0; ni < 8; ++ni) {
    int colL = ni * 16 + l15;
    float bi = biasBuf[biasOff + colL];
    #pragma unroll
    for (int rr = 0; rr < 4; ++rr) {
      int row = m0 + rl0 + rr;
      float o = acc[ni][rr] + bi;
      if (MODE == 1) {
        o = fmaxf(o, 0.0f);
      } else if (row < M) {
        size_t idx = (size_t)(rowbase + row) * 128 + colL;
        float xo = bf16_to_f(xh_all[idx]) + bf16_to_f(xl_all[idx]);
        o = g * o + (1.0f - g) * xo;
      }
      acc[ni][rr] = o;
    }
  }

  const int wrow = tid >> 2, wseg = tid & 3;
  #pragma unroll
  for (int ph = 0; ph < 2; ++ph) {
    if (ph) __syncthreads();
    #pragma unroll
    for (int ni = 0; ni < 8; ++ni) {
      #pragma unroll
      for (int rr = 0; rr < 4; ++rr) {
        u16 hh, ll;
        split2(acc[ni][rr], hh, ll);
        smem[(rl0 + rr) * 136 + ni * 16 + l15] = ph ? ll : hh;
      }
    }
    __syncthreads();
    int grow = m0 + wrow;
    if (grow < M) {
      u16* dstp = ph ? xl_all : xh_all;
      uint4* dst = (uint4*)&dstp[(size_t)(rowbase + grow) * 128 + wseg * 32];
      const uint4* src = (const uint4*)&smem[wrow * 136 + wseg * 32];
      #pragma unroll
      for (int j = 0; j < 4; ++j) dst[j] = src[j];
    }
  }
}

// ---------------- q/kv projection GEMM: 1-term bf16 (xh @ Bh), staged coalesced epilogue ----
// last=1 skips layer-2-dead slabs: kvB2 (nt0 y3,4) and q1 (nt1 y0).
__global__ __launch_bounds__(256) void proj_all(
    const u16* __restrict__ xh_all,
    const u16* __restrict__ Bth, const float* __restrict__ biasBuf,
    u16* __restrict__ q_all, u16* __restrict__ kvA,
    u16* __restrict__ kvB1, u16* __restrict__ kvB2, int last) {
  int bid = blockIdx.x, y = blockIdx.y;
  int nt = (bid < NB0) ? 0 : 1;
  if (nt == 1 && y >= 3) return;
  if (last) {
    if (nt == 0 && y >= 3) return;
    if (nt == 1 && y == 0) return;
  }
  __shared__ u16 smem[10240];  // Ah@0 [128][40], Bh@5120 [128][40]; epilogue reuses @0 [64][136]
  constexpr int AH = 0, BH = 5120;
  int m0 = nt ? (bid - NB0) * 128 : bid * 128;
  int M = nt ? NQ : NC;
  int abase = nt ? NC : 0;
  int bslab = nt ? 5 + y : y;
  u16* cp; int ld, cb, crowbase;
  if (nt == 0) {
    switch (y) {
      case 0: cp = q_all; ld = 128; cb = 0; crowbase = 0; break;
      case 1: cp = kvB1; ld = 256; cb = 0; crowbase = 0; break;
      case 2: cp = kvB1; ld = 256; cb = 128; crowbase = 0; break;
      case 3: cp = kvB2; ld = 256; cb = 0; crowbase = 0; break;
      default: cp = kvB2; ld = 256; cb = 128; crowbase = 0; break;
    }
  } else {
    switch (y) {
      case 0: cp = q_all; ld = 128; cb = 0; crowbase = NC; break;
      case 1: cp = kvA; ld = 256; cb = 0; crowbase = 0; break;
      default: cp = kvA; ld = 256; cb = 128; crowbase = 0; break;
    }
  }
  const int tid = threadIdx.x, lane = tid & 63, wv = tid >> 6;
  const int l15 = lane & 15, g4 = lane >> 4, koff = g4 * 8;
  const int sr = tid >> 1, sc = (tid & 1) * 16;
  const bool rowok = (m0 + sr) < M;

  f32x4 acc[2][8];
  #pragma unroll
  for (int mi = 0; mi < 2; ++mi)
    #pragma unroll
    for (int ni = 0; ni < 8; ++ni) acc[mi][ni] = (f32x4){0.f, 0.f, 0.f, 0.f};

  for (int k0 = 0; k0 < 128; k0 += 32) {
    uint4 h0 = {0, 0, 0, 0}, h1 = {0, 0, 0, 0};
    if (rowok) {
      const u16* ap = xh_all + (size_t)(abase + m0 + sr) * 128 + k0 + sc;
      h0 = *(const uint4*)ap;
      h1 = *(const uint4*)(ap + 8);
    }
    *(uint4*)&smem[AH + sr * 40 + sc] = h0;
    *(uint4*)&smem[AH + sr * 40 + sc + 8] = h1;
    {
      const u16* bp = Bth + (size_t)(bslab * 128 + sr) * 128 + k0 + sc;
      *(uint4*)&smem[BH + sr * 40 + sc] = *(const uint4*)bp;
      *(uint4*)&smem[BH + sr * 40 + sc + 8] = *(const uint4*)(bp + 8);
    }
    __syncthreads();

    bf16x8 a_h[2];
    #pragma unroll
    for (int mi = 0; mi < 2; ++mi) {
      int row = wv * 32 + mi * 16 + l15;
      a_h[mi] = *(const bf16x8*)&smem[AH + row * 40 + koff];
    }
    #pragma unroll
    for (int ni = 0; ni < 8; ++ni) {
      int col = ni * 16 + l15;
      bf16x8 b_h = *(const bf16x8*)&smem[BH + col * 40 + koff];
      #pragma unroll
      for (int mi = 0; mi < 2; ++mi)
        acc[mi][ni] = __builtin_amdgcn_mfma_f32_16x16x32_bf16(a_h[mi], b_h, acc[mi][ni], 0, 0, 0);
    }
    __syncthreads();
  }

  const int wrow = tid >> 2, wseg = tid & 3;
  #pragma unroll
  for (int h = 0; h < 2; ++h) {
    if (h) __syncthreads();
    if ((wv >> 1) == h) {
      #pragma unroll
      for (int mi = 0; mi < 2; ++mi) {
        int rl = (wv & 1) * 32 + mi * 16 + g4 * 4;
        #pragma unroll
        for (int ni = 0; ni < 8; ++ni) {
          float bi = biasBuf[bslab * 128 + ni * 16 + l15];
          #pragma unroll
          for (int rr = 0; rr < 4; ++rr)
            smem[(rl + rr) * 136 + ni * 16 + l15] = bf16_rne(acc[mi][ni][rr] + bi);
        }
      }
    }
    __syncthreads();
    int grow = m0 + h * 64 + wrow;
    if (grow < M) {
      uint4* dst = (uint4*)&cp[(size_t)(crowbase + grow) * ld + cb + wseg * 32];
      const uint4* src = (const uint4*)&smem[wrow * 136 + wseg * 32];
      #pragma unroll
      for (int j = 0; j < 4; ++j) dst[j] = src[j];
    }
  }
}

// ---------------- attention: pair-per-wave, 4 edges/iter (2 per half), exp2 softmax ---------
__device__ __forceinline__ void attn_seg(
    const u16* __restrict__ kv, int start, int end,
    const int* __restrict__ srcs, const float q8[8], int lane, float accO[8]) {
  if (start >= end) return;
  float sum = 0.0f;
  float acc[8];
  #pragma unroll
  for (int i = 0; i < 8; ++i) acc[i] = 0.0f;
  const int half = lane >> 5;
  const int sub = lane & 31;
  const int bsrc = lane & 44;  // k-lane of this head in this half
  for (int e = start; e < end; e += 4) {
    int e0 = e + half;
    int e1 = e + 2 + half;
    bool v0 = e0 < end, v1 = e1 < end;
    int c0 = v0 ? e0 : end - 1;
    int c1 = v1 ? e1 : end - 1;
    int s0 = srcs[c0];
    int s1 = srcs[c1];
    uint4 u0 = *(const uint4*)&kv[(size_t)s0 * 256 + sub * 8];
    uint4 u1 = *(const uint4*)&kv[(size_t)s1 * 256 + sub * 8];
    float r0[8], r1[8];
    r0[0] = bf16_to_f((u16)(u0.x & 0xffffu)); r0[1] = bf16_to_f((u16)(u0.x >> 16));
    r0[2] = bf16_to_f((u16)(u0.y & 0xffffu)); r0[3] = bf16_to_f((u16)(u0.y >> 16));
    r0[4] = bf16_to_f((u16)(u0.z & 0xffffu)); r0[5] = bf16_to_f((u16)(u0.z >> 16));
    r0[6] = bf16_to_f((u16)(u0.w & 0xffffu)); r0[7] = bf16_to_f((u16)(u0.w >> 16));
    r1[0] = bf16_to_f((u16)(u1.x & 0xffffu)); r1[1] = bf16_to_f((u16)(u1.x >> 16));
    r1[2] = bf16_to_f((u16)(u1.y & 0xffffu)); r1[3] = bf16_to_f((u16)(u1.y >> 16));
    r1[4] = bf16_to_f((u16)(u1.z & 0xffffu)); r1[5] = bf16_to_f((u16)(u1.z >> 16));
    r1[6] = bf16_to_f((u16)(u1.w & 0xffffu)); r1[7] = bf16_to_f((u16)(u1.w >> 16));
    float p0 = q8[0] * r0[0];
    float p1 = q8[0] * r1[0];
    #pragma unroll
    for (int i = 1; i < 8; ++i) {
      p0 = fmaf(q8[i], r0[i], p0);
      p1 = fmaf(q8[i], r1[i], p1);
    }
    p0 += __shfl_xor(p0, 1);
    p1 += __shfl_xor(p1, 1);
    p0 += __shfl_xor(p0, 2);
    p1 += __shfl_xor(p1, 2);
    p0 = fminf(p0, 100.0f);
    p1 = fminf(p1, 100.0f);
    float w0 = v0 ? exp2f(p0) : 0.0f;
    float w1 = v1 ? exp2f(p1) : 0.0f;
    float wB0 = __shfl(w0, bsrc);
    float wB1 = __shfl(w1, bsrc);
    sum += wB0 + wB1;
    #pragma unroll
    for (int i = 0; i < 8; ++i) {
      acc[i] = fmaf(wB0, r0[i], acc[i]);
      acc[i] = fmaf(wB1, r1[i], acc[i]);
    }
  }
  sum += __shfl_xor(sum, 32);
  #pragma unroll
  for (int i = 0; i < 8; ++i) acc[i] += __shfl_xor(acc[i], 32);
  float inv = 1.0f / (sum + 1e-16f);
  #pragma unroll
  for (int i = 0; i < 8; ++i) accO[i] = fmaf(acc[i], inv, accO[i]);
}

// ncap: number of dst nodes processed (NTOT2 for layer 1, NC for last layer — et2 dead)
__global__ __launch_bounds__(256) void attn_all(
    const u16* __restrict__ q_all, const u16* __restrict__ kvA,
    const u16* __restrict__ kvB1, const u16* __restrict__ kvB2,
    const int* __restrict__ ptr_all, const int* __restrict__ srcs_all,
    float* __restrict__ agg_all, int ncap) {
  int wave = threadIdx.x >> 6, lane = threadIdx.x & 63;
  int node = blockIdx.x * 4 + wave;
  if (node >= ncap) return;
  int sub = lane & 31;
  float q8[8];
  #pragma unroll
  for (int i = 0; i < 8; ++i) q8[i] = 0.0f;
  if (sub < 16) {
    uint4 u = *(const uint4*)&q_all[(size_t)node * 128 + sub * 8];
    q8[0] = bf16_to_f((u16)(u.x & 0xffffu)) * LOG2E; q8[1] = bf16_to_f((u16)(u.x >> 16)) * LOG2E;
    q8[2] = bf16_to_f((u16)(u.y & 0xffffu)) * LOG2E; q8[3] = bf16_to_f((u16)(u.y >> 16)) * LOG2E;
    q8[4] = bf16_to_f((u16)(u.z & 0xffffu)) * LOG2E; q8[5] = bf16_to_f((u16)(u.z >> 16)) * LOG2E;
    q8[6] = bf16_to_f((u16)(u.w & 0xffffu)) * LOG2E; q8[7] = bf16_to_f((u16)(u.w >> 16)) * LOG2E;
  }
  float accO[8];
  #pragma unroll
  for (int i = 0; i < 8; ++i) accO[i] = 0.0f;
  if (node < NC) {
    attn_seg(kvA, ptr_all[node], ptr_all[node + 1], srcs_all, q8, lane, accO);
    attn_seg(kvB1, ptr_all[NC + node], ptr_all[NC + node + 1], srcs_all, q8, lane, accO);
  } else {
    int idx = 2 * NC + (node - NC);
    attn_seg(kvB2, ptr_all[idx], ptr_all[idx + 1], srcs_all, q8, lane, accO);
  }
  if (lane >= 16 && lane < 32) {
    int j = lane - 16;
    float4 o0 = {accO[0], accO[1], accO[2], accO[3]};
    float4 o1 = {accO[4], accO[5], accO[6], accO[7]};
    *(float4*)&agg_all[(size_t)node * 128 + j * 8] = o0;
    *(float4*)&agg_all[(size_t)node * 128 + j * 8 + 4] = o1;
  }
}

// ---------------- final projection ----------------
__global__ __launch_bounds__(256) void gemm_out(const u16* __restrict__ Xh,
                                                const u16* __restrict__ Xl,
                                                const float* __restrict__ W,
                                                const float* __restrict__ b,
                                                float* __restrict__ out, int M) {
  __shared__ float Ws[1024];
  __shared__ float As[32][129];
  int tid = threadIdx.x;
  int m0 = blockIdx.x * 32;
  *(float4*)&Ws[tid * 4] = *(const float4*)&W[tid * 4];
  {
    int r = tid >> 3;
    int c0 = (tid & 7) * 16;
    if (m0 + r < M) {
      const u16* hp = Xh + (size_t)(m0 + r) * 128 + c0;
      const u16* lp = Xl + (size_t)(m0 + r) * 128 + c0;
      #pragma unroll
      for (int j = 0; j < 16; ++j) As[r][c0 + j] = bf16_to_f(hp[j]) + bf16_to_f(lp[j]);
    } else {
      #pragma unroll
      for (int j = 0; j < 16; ++j) As[r][c0 + j] = 0.0f;
    }
  }
  __syncthreads();
  int r = tid >> 3, c = tid & 7;
  float sum = b[c];
  #pragma unroll 16
  for (int k = 0; k < 128; ++k) sum = fmaf(As[r][k], Ws[k * 8 + c], sum);
  if (m0 + r < M) out[(size_t)(m0 + r) * 8 + c] = sum;
}

// ---------------- host orchestration ----------------
static inline size_t align256(size_t x) { return (x + 255) & ~(size_t)255; }

extern "C" void kernel_launch(void* const* d_in, const int* in_sizes, int n_in,
                              void* d_out, int out_size, void* d_ws, size_t ws_size,
                              hipStream_t stream) {
  const float* x_context = (const float*)d_in[0];
  const float* x_question = (const float*)d_in[1];
  const int* src_q2c = (const int*)d_in[2];
  const int* dst_q2c = (const int*)d_in[3];
  const int* src_c2c = (const int*)d_in[4];
  const int* dst_c2c = (const int*)d_in[5];
  const int* src_c2q = (const int*)d_in[6];
  const int* dst_c2q = (const int*)d_in[7];
  const float* inWc = (const float*)d_in[8];
  const float* inbc = (const float*)d_in[9];
  const float* inWq = (const float*)d_in[10];
  const float* inbq = (const float*)d_in[11];
  const float* kW = (const float*)d_in[12];
  const float* kB = (const float*)d_in[13];
  const float* qW = (const float*)d_in[14];
  const float* qB = (const float*)d_in[15];
  const float* vW = (const float*)d_in[16];
  const float* vB = (const float*)d_in[17];
  const float* aW = (const float*)d_in[18];
  const float* aB = (const float*)d_in[19];
  const float* skip = (const float*)d_in[20];
  const float* arel = (const float*)d_in[21];
  const float* mrel = (const float*)d_in[22];
  const float* prel = (const float*)d_in[23];
  const float* outW = (const float*)d_in[24];
  const float* outb = (const float*)d_in[25];

  char* base = (char*)d_ws;
  size_t off = 0;
  auto carve = [&](size_t bytes) -> void* {
    void* p = base + off;
    off = align256(off + bytes);
    return p;
  };
  u16* xh_all = (u16*)carve((size_t)NTOT2 * 128 * 2);
  u16* xl_all = (u16*)carve((size_t)NTOT2 * 128 * 2);
  u16* q_all = (u16*)carve((size_t)NTOT2 * 128 * 2);
  u16* kvA = (u16*)carve((size_t)NQ * 256 * 2);
  u16* kvB1 = (u16*)carve((size_t)NC * 256 * 2);
  u16* kvB2 = (u16*)carve((size_t)NC * 256 * 2);
  float* agg_all = (float*)carve((size_t)NTOT2 * 128 * 4);
  u16* Bth = (u16*)carve((size_t)2560 * 128 * 2);   // 20 slabs (both layers)
  u16* Btl = (u16*)carve((size_t)2560 * 128 * 2);
  u16* BthI = (u16*)carve((size_t)(320 + 768) * 128 * 2);
  u16* BtlI = (u16*)carve((size_t)(320 + 768) * 128 * 2);
  float* biasBuf = (float*)carve(2560 * 4);
  float* biasIn = (float*)carve(256 * 4);
  int* ptr_all = (int*)carve((size_t)(NTOT + 1) * 4);
  int* srcs_all = (int*)carve((size_t)3 * NEDGE * 4);
  int* counts = (int*)carve((size_t)NTOT * 4);
  int* cursor = (int*)carve((size_t)NTOT * 4);
  int* blksums = (int*)carve(2048 * 4);

  // ---- fused CSR build ----
  {
    int nb = (NTOT + 255) / 256;
    hipMemsetAsync(counts, 0, (size_t)NTOT * 4, stream);
    k_count3<<<(3 * NEDGE + 255) / 256, 256, 0, stream>>>(dst_q2c, dst_c2c, dst_c2q, counts);
    k_scan_block<<<nb, 256, 0, stream>>>(counts, ptr_all, blksums, NTOT);
    k_scan_sums<<<1, 1024, 0, stream>>>(blksums, nb);
    k_scan_add<<<nb, 256, 0, stream>>>(ptr_all, blksums, cursor, NTOT, 3 * NEDGE);
    k_scatter3<<<(3 * NEDGE + 255) / 256, 256, 0, stream>>>(
        src_q2c, src_c2c, src_c2q, dst_q2c, dst_c2c, dst_c2q, cursor, srcs_all);
  }

  // ---- weight prep (input + both layers) ----
  split_in<<<dim3(128, 2), 256, 0, stream>>>(inWc, inbc, inWq, inbq, BthI, BtlI, biasIn);
  prep_all<<<dim3(128, 20), 128, 0, stream>>>(kW, kB, qW, qB, vW, vB, aW, aB,
                                              arel, mrel, prel, Bth, Btl, biasBuf);

  // ---- input projections (pipelined) ----
  pipe_gemm<1><<<NBALL64, 256, 0, stream>>>(x_context, x_question, BthI, BtlI, biasIn,
                                            xh_all, xl_all, nullptr, 0);

  for (int l = 0; l < 2; ++l) {
    const int last = (l == 1);
    const u16* BthL = Bth + (size_t)l * 10 * 128 * 128;
    const u16* BtlL = Btl + (size_t)l * 10 * 128 * 128;
    const float* biasL = biasBuf + (size_t)l * 1280;
    proj_all<<<dim3(NBALL, 5), 256, 0, stream>>>(xh_all, BthL, biasL,
                                                 q_all, kvA, kvB1, kvB2, last);
    int ncap = last ? NC : NTOT2;
    attn_all<<<(ncap + 3) / 4, 256, 0, stream>>>(q_all, kvA, kvB1, kvB2,
                                                 ptr_all, srcs_all, agg_all, ncap);
    pipe_gemm<2><<<last ? NBC64 : NBALL64, 256, 0, stream>>>(agg_all, nullptr, BthL, BtlL, biasL,
                                                             xh_all, xl_all, skip, l);
  }

  gemm_out<<<(NC + 31) / 32, 256, 0, stream>>>(xh_all, xl_all, outW, outb, (float*)d_out, NC);
}